// Round 3
// baseline (205.304 us; speedup 1.0000x reference)
//
#include <hip/hip_runtime.h>

#define DIN 768

typedef float f2 __attribute__((ext_vector_type(2)));

__device__ __forceinline__ int swz(int i) { return i ^ ((i >> 4) & 31); }

// Composite gather map of the CNOT ring CNOT(0,1)..CNOT(9,0): Final[i] = In[cnotL(i)]
__device__ __forceinline__ int cnotL(int i) {
  const int b9 = (i >> 9) & 1;
  const int b8 = (i >> 8) & 1;
  const int b0 = i & 1;
  return ((i ^ (i >> 1)) & 0xFF) | ((b8 ^ b9 ^ b0) << 8) | ((b9 ^ b0) << 9);
}

__device__ __forceinline__ f2 shfl_xor_f2(f2 v, int mask) {
  f2 r;
  r.x = __shfl_xor(v.x, mask);
  r.y = __shfl_xor(v.y, mask);
  return r;
}

// ---------- real-state (round 1) gates ----------
template<int RB>
__device__ __forceinline__ void ry_reg_real(float (&sr)[16], float c, float s) {
#pragma unroll
  for (int r = 0; r < 16; ++r) {
    if (!(r & (1 << RB))) {
      const int r1 = r | (1 << RB);
      const float a0 = sr[r], a1 = sr[r1];
      sr[r]  = c * a0 - s * a1;
      sr[r1] = s * a0 + c * a1;
    }
  }
}

template<int MASK>
__device__ __forceinline__ void ry_shfl_real(int lane, float (&sr)[16], float c, float s) {
  const float ss = (lane & MASK) ? s : -s;
#pragma unroll
  for (int r = 0; r < 16; ++r) {
    const float p = __shfl_xor(sr[r], MASK);
    sr[r] = fmaf(ss, p, c * sr[r]);
  }
}

// ---------- complex (packed f32x2) gates ----------
template<int RB>
__device__ __forceinline__ void ry_reg(f2 (&s)[16], float c, float sn) {
#pragma unroll
  for (int r = 0; r < 16; ++r) {
    if (!(r & (1 << RB))) {
      const int r1 = r | (1 << RB);
      const f2 a0 = s[r], a1 = s[r1];
      s[r]  = a0 * c - a1 * sn;   // v_pk_mul + v_pk_fma
      s[r1] = a1 * c + a0 * sn;
    }
  }
}

template<int MASK>
__device__ __forceinline__ void ry_shfl(int lane, f2 (&s)[16], float c, float sn) {
  const float ss = (lane & MASK) ? sn : -sn;
#pragma unroll
  for (int r = 0; r < 16; ++r) {
    const f2 p = shfl_xor_f2(s[r], MASK);
    s[r] = s[r] * c + p * ss;
  }
}

// RZ on all 10 qubits, layout B (i = (r<<6)|lane).
__device__ __forceinline__ void rz_apply(int lane, const float* __restrict__ w, int off, f2 (&s)[16]) {
  float phiL = 0.f;
#pragma unroll
  for (int j = 0; j < 6; ++j) {               // lane bit j <-> qubit 9-j
    const float h = 0.5f * w[off + 9 - j];
    phiL += ((lane >> j) & 1) ? h : -h;
  }
  const float h0 = 0.5f * w[off + 0];          // r bit 3 <-> qubit 0
  const float h1 = 0.5f * w[off + 1];
  const float h2 = 0.5f * w[off + 2];
  const float h3 = 0.5f * w[off + 3];
  const float base = phiL - h0 - h1 - h2 - h3;
#pragma unroll
  for (int r = 0; r < 16; ++r) {
    float ang = base;
    if (r & 8) ang += 2.f * h0;
    if (r & 4) ang += 2.f * h1;
    if (r & 2) ang += 2.f * h2;
    if (r & 1) ang += 2.f * h3;
    float sn, cn;
    __sincosf(ang, &sn, &cn);
    const f2 v = s[r];
    const f2 sw = { -v.y, v.x };               // i * v
    s[r] = v * cn + sw * sn;
  }
}

// ---------- wave-private LDS transposes (no barriers: one wave owns stf) ----------
// A: i = (lane<<4)|r ; B: i = (r<<6)|lane. DS ops from one wave execute in order.
__device__ __forceinline__ void transT_real_AB(float* stf, int lane, float (&sr)[16]) {
#pragma unroll
  for (int r = 0; r < 16; ++r) stf[swz((lane << 4) | r)] = sr[r];
#pragma unroll
  for (int r = 0; r < 16; ++r) sr[r] = stf[swz((r << 6) | lane)];
}

__device__ __forceinline__ void trans_AB(float* stf, int lane, f2 (&s)[16]) {
#pragma unroll
  for (int r = 0; r < 16; ++r) stf[swz((lane << 4) | r)] = s[r].x;
#pragma unroll
  for (int r = 0; r < 16; ++r) s[r].x = stf[swz((r << 6) | lane)];
#pragma unroll
  for (int r = 0; r < 16; ++r) stf[swz((lane << 4) | r)] = s[r].y;
#pragma unroll
  for (int r = 0; r < 16; ++r) s[r].y = stf[swz((r << 6) | lane)];
}

__device__ __forceinline__ void trans_cnot_BA(float* stf, int lane, f2 (&s)[16]) {
#pragma unroll
  for (int r = 0; r < 16; ++r) stf[swz((r << 6) | lane)] = s[r].x;
#pragma unroll
  for (int r = 0; r < 16; ++r) s[r].x = stf[swz(cnotL((lane << 4) | r))];
#pragma unroll
  for (int r = 0; r < 16; ++r) stf[swz((r << 6) | lane)] = s[r].y;
#pragma unroll
  for (int r = 0; r < 16; ++r) s[r].y = stf[swz(cnotL((lane << 4) | r))];
}

// ---------- expectation values (layout B) ----------
template<int RB, int Q>
__device__ __forceinline__ void xy_reg(const f2 (&s)[16], float (&acc)[18]) {
#pragma unroll
  for (int r = 0; r < 16; ++r) {
    if (!(r & (1 << RB))) {
      const int r1 = r | (1 << RB);
      const f2 t = s[r] * s[r1];                    // (r0*r1, i0*i1)
      acc[Q] = fmaf(2.f, t.x + t.y, acc[Q]);
      const f2 u = s[r] * (f2){ s[r1].y, s[r1].x }; // (r0*i1, i0*r1)
      acc[Q + 6] = fmaf(2.f, u.x - u.y, acc[Q + 6]);
    }
  }
}

template<int MASK, int Q>
__device__ __forceinline__ void xy_shfl(int lane, const f2 (&s)[16], float (&acc)[18]) {
  const float sgn = (lane & MASK) ? -1.f : 1.f;
#pragma unroll
  for (int r = 0; r < 16; ++r) {
    const f2 p = shfl_xor_f2(s[r], MASK);
    const f2 t = s[r] * p;
    acc[Q] += t.x + t.y;                          // pair double-counted -> net 2x
    const f2 u = s[r] * (f2){ p.y, p.x };
    acc[Q + 6] += sgn * (u.x - u.y);
  }
}

__global__ __launch_bounds__(256) void qae_kernel(const float* __restrict__ x,
                                                  const float* __restrict__ w,
                                                  float* __restrict__ out, int Btot) {
  __shared__ float stf_all[4 * 1024];   // wave-private 4KB regions
  __shared__ float2 tab[70];            // (cos, sin) half-angles; [60..69] folded round

  const int tid  = threadIdx.x;
  const int lane = tid & 63;
  const int wid  = tid >> 6;
  const int b    = blockIdx.x * 4 + wid;
  float* stf = stf_all + (wid << 10);

  if (tid < 60) {                       // all in wave 0
    float s, c;
    __sincosf(0.5f * w[tid], &s, &c);
    tab[tid] = make_float2(c, s);
  }
  if (tid < 10) {                       // RY_b(layer1) + RY_c(layer2) folded
    float s, c;
    __sincosf(0.5f * (w[20 + tid] + w[30 + tid]), &s, &c);
    tab[60 + tid] = make_float2(c, s);
  }
  __syncthreads();                      // the ONLY block-wide barrier
  if (b >= Btot) return;

  // Load row in layout A: amplitude i = (lane<<4)|r ; i >= 768 zero pad.
  float sr[16];
  float sumsq = 0.f;
  const float* xb = x + (size_t)b * DIN;
#pragma unroll
  for (int k = 0; k < 4; ++k) {
    const int idx = lane * 16 + 4 * k;
    float4 v = make_float4(0.f, 0.f, 0.f, 0.f);
    if (idx < DIN) v = *reinterpret_cast<const float4*>(xb + idx);
    sr[4*k+0] = v.x; sr[4*k+1] = v.y; sr[4*k+2] = v.z; sr[4*k+3] = v.w;
    sumsq += v.x*v.x; sumsq += v.y*v.y; sumsq += v.z*v.z; sumsq += v.w*v.w;
  }
#pragma unroll
  for (int m = 32; m >= 1; m >>= 1) sumsq += __shfl_xor(sumsq, m);
  const float inv_n2 = 1.f / fmaxf(sumsq, 1e-16f);  // deferred normalization

  float2 cs;
  // ===== layer 1 RY round (w[0..9]) — REAL state =====
  cs = tab[6]; ry_reg_real<3>(sr, cs.x, cs.y);        // A: q6 -> r bit 3
  cs = tab[7]; ry_reg_real<2>(sr, cs.x, cs.y);
  cs = tab[8]; ry_reg_real<1>(sr, cs.x, cs.y);
  cs = tab[9]; ry_reg_real<0>(sr, cs.x, cs.y);
  cs = tab[4]; ry_shfl_real<2>(lane, sr, cs.x, cs.y); // A: q4 -> lane bit 1
  cs = tab[5]; ry_shfl_real<1>(lane, sr, cs.x, cs.y); // A: q5 -> lane bit 0

  transT_real_AB(stf, lane, sr);                      // T1

  cs = tab[0]; ry_reg_real<3>(sr, cs.x, cs.y);        // B: q0 -> r bit 3
  cs = tab[1]; ry_reg_real<2>(sr, cs.x, cs.y);
  cs = tab[2]; ry_reg_real<1>(sr, cs.x, cs.y);
  cs = tab[3]; ry_reg_real<0>(sr, cs.x, cs.y);

  // RZ layer 1 (w[10..19]): real -> complex packed
  f2 s[16];
  {
    float phiL = 0.f;
#pragma unroll
    for (int j = 0; j < 6; ++j) {
      const float h = 0.5f * w[10 + 9 - j];
      phiL += ((lane >> j) & 1) ? h : -h;
    }
    const float h0 = 0.5f*w[10], h1 = 0.5f*w[11], h2 = 0.5f*w[12], h3 = 0.5f*w[13];
    const float base = phiL - h0 - h1 - h2 - h3;
#pragma unroll
    for (int r = 0; r < 16; ++r) {
      float ang = base;
      if (r & 8) ang += 2.f*h0;
      if (r & 4) ang += 2.f*h1;
      if (r & 2) ang += 2.f*h2;
      if (r & 1) ang += 2.f*h3;
      float sn, cn;
      __sincosf(ang, &sn, &cn);
      s[r] = (f2){ sr[r] * cn, sr[r] * sn };
    }
  }

  trans_cnot_BA(stf, lane, s);                        // T2: CNOT ring 1

  // ===== combined RY: layer1 RY_b + layer2 RY_c =====
  cs = tab[66]; ry_reg<3>(s, cs.x, cs.y);
  cs = tab[67]; ry_reg<2>(s, cs.x, cs.y);
  cs = tab[68]; ry_reg<1>(s, cs.x, cs.y);
  cs = tab[69]; ry_reg<0>(s, cs.x, cs.y);
  cs = tab[64]; ry_shfl<2>(lane, s, cs.x, cs.y);
  cs = tab[65]; ry_shfl<1>(lane, s, cs.x, cs.y);

  trans_AB(stf, lane, s);                             // T3

  cs = tab[60]; ry_reg<3>(s, cs.x, cs.y);
  cs = tab[61]; ry_reg<2>(s, cs.x, cs.y);
  cs = tab[62]; ry_reg<1>(s, cs.x, cs.y);
  cs = tab[63]; ry_reg<0>(s, cs.x, cs.y);

  rz_apply(lane, w, 40, s);                           // RZ layer 2

  trans_cnot_BA(stf, lane, s);                        // T4: CNOT ring 2

  // ===== final RY round (w[50..59]) =====
  cs = tab[56]; ry_reg<3>(s, cs.x, cs.y);
  cs = tab[57]; ry_reg<2>(s, cs.x, cs.y);
  cs = tab[58]; ry_reg<1>(s, cs.x, cs.y);
  cs = tab[59]; ry_reg<0>(s, cs.x, cs.y);
  cs = tab[54]; ry_shfl<2>(lane, s, cs.x, cs.y);
  cs = tab[55]; ry_shfl<1>(lane, s, cs.x, cs.y);

  trans_AB(stf, lane, s);                             // T5

  cs = tab[50]; ry_reg<3>(s, cs.x, cs.y);
  cs = tab[51]; ry_reg<2>(s, cs.x, cs.y);
  cs = tab[52]; ry_reg<1>(s, cs.x, cs.y);
  cs = tab[53]; ry_reg<0>(s, cs.x, cs.y);

  // ===== expectation values (layout B) =====
  float acc[18];
#pragma unroll
  for (int k = 0; k < 12; ++k) acc[k] = 0.f;

  float psum = 0.f;
  {
    float a12 = 0.f, a13 = 0.f, a14 = 0.f, a15 = 0.f;
#pragma unroll
    for (int r = 0; r < 16; ++r) {
      const f2 t = s[r] * s[r];
      const float p = t.x + t.y;
      psum += p;
      a12 += (r & 8) ? -p : p;     // Z q0
      a13 += (r & 4) ? -p : p;     // Z q1
      a14 += (r & 2) ? -p : p;     // Z q2
      a15 += (r & 1) ? -p : p;     // Z q3
    }
    acc[12] = a12; acc[13] = a13; acc[14] = a14; acc[15] = a15;
    acc[16] = ((lane >> 5) & 1) ? -psum : psum;   // Z q4
    acc[17] = ((lane >> 4) & 1) ? -psum : psum;   // Z q5
  }

  xy_reg<3,0>(s, acc);
  xy_reg<2,1>(s, acc);
  xy_reg<1,2>(s, acc);
  xy_reg<0,3>(s, acc);
  xy_shfl<32,4>(lane, s, acc);
  xy_shfl<16,5>(lane, s, acc);

#pragma unroll
  for (int k = 0; k < 18; ++k) {
#pragma unroll
    for (int m = 32; m >= 1; m >>= 1) acc[k] += __shfl_xor(acc[k], m);
  }

  if (lane == 0) {
    float* ob = out + (size_t)b * 18;
#pragma unroll
    for (int k = 0; k < 18; ++k) ob[k] = acc[k] * inv_n2;
  }
}

extern "C" void kernel_launch(void* const* d_in, const int* in_sizes, int n_in,
                              void* d_out, int out_size, void* d_ws, size_t ws_size,
                              hipStream_t stream) {
  const float* x = (const float*)d_in[0];
  const float* w = (const float*)d_in[1];
  float* out = (float*)d_out;
  const int B = in_sizes[0] / DIN;
  const int grid = (B + 3) / 4;
  qae_kernel<<<dim3(grid), dim3(256), 0, stream>>>(x, w, out, B);
}

// Round 4
// 173.494 us; speedup vs baseline: 1.1834x; 1.1834x over previous
//
#include <hip/hip_runtime.h>

#define DIN 768

typedef float f2 __attribute__((ext_vector_type(2)));

// R2-proven swizzle for the 1024-cell complex f2 array (conflict-free incl. cnot gather)
__device__ __forceinline__ int swz(int i) { return i ^ ((i >> 4) & 31); }
// swizzle for the 512-cell real-pair f2 array (conflict-free on A-write and B-read)
__device__ __forceinline__ int swzr(int i) { return i ^ ((i >> 4) & 31); }

// Composite gather map of the CNOT ring CNOT(0,1)..CNOT(9,0): Final[i] = In[cnotL(i)]
__device__ __forceinline__ int cnotL(int i) {
  const int b9 = (i >> 9) & 1;
  const int b8 = (i >> 8) & 1;
  const int b0 = i & 1;
  return ((i ^ (i >> 1)) & 0xFF) | ((b8 ^ b9 ^ b0) << 8) | ((b9 ^ b0) << 9);
}

__device__ __forceinline__ f2 shfl_xor_f2(f2 v, int mask) {
  f2 r;
  r.x = __shfl_xor(v.x, mask);
  r.y = __shfl_xor(v.y, mask);
  return r;
}

// ---------- real-state gates, packed: h[j] = (amp(2j), amp(2j+1)) ----------
template<int JB>
__device__ __forceinline__ void ry_real_pk(f2 (&h)[8], float c, float s) {
#pragma unroll
  for (int j = 0; j < 8; ++j) {
    if (!(j & (1 << JB))) {
      const int p = j | (1 << JB);
      const f2 a0 = h[j], a1 = h[p];
      h[j] = a0 * c - a1 * s;     // v_pk_mul + v_pk_fma
      h[p] = a1 * c + a0 * s;
    }
  }
}

// gate on the intra-f2 bit (amp pair inside one f2)
__device__ __forceinline__ void ry_real_intra(f2 (&h)[8], float c, float s) {
  const f2 ssv = { -s, s };
#pragma unroll
  for (int j = 0; j < 8; ++j) {
    const f2 a = h[j];
    const f2 sw = { a.y, a.x };
    h[j] = sw * ssv + a * c;       // (c*x - s*y, s*x + c*y)
  }
}

template<int MASK>
__device__ __forceinline__ void ry_shfl_real_pk(int lane, f2 (&h)[8], float c, float s) {
  const float ss = (lane & MASK) ? s : -s;
#pragma unroll
  for (int j = 0; j < 8; ++j) {
    const f2 p = shfl_xor_f2(h[j], MASK);
    h[j] = h[j] * c + p * ss;
  }
}

// ---------- complex (packed re/im) gates ----------
template<int RB>
__device__ __forceinline__ void ry_reg(f2 (&s)[16], float c, float sn) {
#pragma unroll
  for (int r = 0; r < 16; ++r) {
    if (!(r & (1 << RB))) {
      const int r1 = r | (1 << RB);
      const f2 a0 = s[r], a1 = s[r1];
      s[r]  = a0 * c - a1 * sn;
      s[r1] = a1 * c + a0 * sn;
    }
  }
}

template<int MASK>
__device__ __forceinline__ void ry_shfl(int lane, f2 (&s)[16], float c, float sn) {
  const float ss = (lane & MASK) ? sn : -sn;
#pragma unroll
  for (int r = 0; r < 16; ++r) {
    const f2 p = shfl_xor_f2(s[r], MASK);
    s[r] = s[r] * c + p * ss;
  }
}

// RZ on all 10 qubits, layout B (i = (r<<6)|lane).
__device__ __forceinline__ void rz_apply(int lane, const float* __restrict__ w, int off, f2 (&s)[16]) {
  float phiL = 0.f;
#pragma unroll
  for (int j = 0; j < 6; ++j) {               // lane bit j <-> qubit 9-j
    const float h = 0.5f * w[off + 9 - j];
    phiL += ((lane >> j) & 1) ? h : -h;
  }
  const float h0 = 0.5f * w[off + 0];          // r bit 3 <-> qubit 0
  const float h1 = 0.5f * w[off + 1];
  const float h2 = 0.5f * w[off + 2];
  const float h3 = 0.5f * w[off + 3];
  const float base = phiL - h0 - h1 - h2 - h3;
#pragma unroll
  for (int r = 0; r < 16; ++r) {
    float ang = base;
    if (r & 8) ang += 2.f * h0;
    if (r & 4) ang += 2.f * h1;
    if (r & 2) ang += 2.f * h2;
    if (r & 1) ang += 2.f * h3;
    float sn, cn;
    __sincosf(ang, &sn, &cn);
    const f2 v = s[r];
    const f2 sw = { -v.y, v.x };               // i * v
    s[r] = v * cn + sw * sn;
  }
}

// ---------- expectation values (layout B) ----------
template<int RB, int Q>
__device__ __forceinline__ void xy_reg(const f2 (&s)[16], float (&acc)[18]) {
#pragma unroll
  for (int r = 0; r < 16; ++r) {
    if (!(r & (1 << RB))) {
      const int r1 = r | (1 << RB);
      const f2 t = s[r] * s[r1];
      acc[Q] = fmaf(2.f, t.x + t.y, acc[Q]);
      const f2 u = s[r] * (f2){ s[r1].y, s[r1].x };
      acc[Q + 6] = fmaf(2.f, u.x - u.y, acc[Q + 6]);
    }
  }
}

template<int MASK, int Q>
__device__ __forceinline__ void xy_shfl(int lane, const f2 (&s)[16], float (&acc)[18]) {
  const float sgn = (lane & MASK) ? -1.f : 1.f;
#pragma unroll
  for (int r = 0; r < 16; ++r) {
    const f2 p = shfl_xor_f2(s[r], MASK);
    const f2 t = s[r] * p;
    acc[Q] += t.x + t.y;                       // pair double-counted -> net 2x
    const f2 u = s[r] * (f2){ p.y, p.x };
    acc[Q + 6] += sgn * (u.x - u.y);
  }
}

__global__ __launch_bounds__(128) void qae_kernel(const float* __restrict__ x,
                                                  const float* __restrict__ w,
                                                  float* __restrict__ out, int Btot) {
  __shared__ f2 st_all[2 * 1024];       // wave-private 8KB regions (complex) / first 4KB (real)
  __shared__ float2 tab[70];            // (cos, sin) half-angles; [60..69] folded round

  const int tid  = threadIdx.x;
  const int lane = tid & 63;
  const int wid  = tid >> 6;
  const int b    = blockIdx.x * 2 + wid;
  f2* stc = st_all + (wid << 10);       // 1024 f2 cells, this wave's region

  if (tid < 60) {                       // all in wave 0
    float s, c;
    __sincosf(0.5f * w[tid], &s, &c);
    tab[tid] = make_float2(c, s);
  }
  if (tid < 10) {                       // RY_b(layer1) + RY_c(layer2) folded
    float s, c;
    __sincosf(0.5f * (w[20 + tid] + w[30 + tid]), &s, &c);
    tab[60 + tid] = make_float2(c, s);
  }
  __syncthreads();                      // the ONLY block-wide barrier
  if (b >= Btot) return;

  // Load row, layout A packed: h[j] = (x[lane*16+2j], x[lane*16+2j+1]); i >= 768 zero.
  f2 h[8];
  float sumsq = 0.f;
  const float* xb = x + (size_t)b * DIN;
#pragma unroll
  for (int t = 0; t < 4; ++t) {
    const int idx = lane * 16 + 4 * t;
    float4 v = make_float4(0.f, 0.f, 0.f, 0.f);
    if (idx < DIN) v = *reinterpret_cast<const float4*>(xb + idx);
    h[2*t]   = (f2){ v.x, v.y };
    h[2*t+1] = (f2){ v.z, v.w };
    sumsq += v.x*v.x; sumsq += v.y*v.y; sumsq += v.z*v.z; sumsq += v.w*v.w;
  }
#pragma unroll
  for (int m = 32; m >= 1; m >>= 1) sumsq += __shfl_xor(sumsq, m);
  const float inv_n2 = 1.f / fmaxf(sumsq, 1e-16f);  // deferred normalization

  float2 cs;
  // ===== layer 1 RY round (w[0..9]) — REAL state, layout A =====
  // A: r bit3..0 <-> qubits 6,7,8,9 ; j bit2..0 <-> q6,q7,q8 ; intra <-> q9
  cs = tab[6]; ry_real_pk<2>(h, cs.x, cs.y);
  cs = tab[7]; ry_real_pk<1>(h, cs.x, cs.y);
  cs = tab[8]; ry_real_pk<0>(h, cs.x, cs.y);
  cs = tab[9]; ry_real_intra(h, cs.x, cs.y);
  cs = tab[4]; ry_shfl_real_pk<2>(lane, h, cs.x, cs.y);  // q4 <-> lane bit 1
  cs = tab[5]; ry_shfl_real_pk<1>(lane, h, cs.x, cs.y);  // q5 <-> lane bit 0

  { // T1: real A->B transpose (512-cell f2 space)
    f2* st2 = stc;                       // first 4KB of this wave's region
#pragma unroll
    for (int j = 0; j < 8; ++j) st2[swzr((lane << 3) | j)] = h[j];
    const float* st1 = reinterpret_cast<const float*>(st2);
#pragma unroll
    for (int j = 0; j < 8; ++j) {
      const int i2a = ((2*j)   << 5) | (lane >> 1);
      const int i2b = ((2*j+1) << 5) | (lane >> 1);
      h[j].x = st1[swzr(i2a) * 2 + (lane & 1)];
      h[j].y = st1[swzr(i2b) * 2 + (lane & 1)];
    }
  }
  // B: j bit2..0 <-> q0,q1,q2 ; intra <-> q3
  cs = tab[0]; ry_real_pk<2>(h, cs.x, cs.y);
  cs = tab[1]; ry_real_pk<1>(h, cs.x, cs.y);
  cs = tab[2]; ry_real_pk<0>(h, cs.x, cs.y);
  cs = tab[3]; ry_real_intra(h, cs.x, cs.y);

  // RZ layer 1 (w[10..19]): real -> complex packed
  f2 s[16];
  {
    float phiL = 0.f;
#pragma unroll
    for (int j = 0; j < 6; ++j) {
      const float hh = 0.5f * w[10 + 9 - j];
      phiL += ((lane >> j) & 1) ? hh : -hh;
    }
    const float h0 = 0.5f*w[10], h1 = 0.5f*w[11], h2 = 0.5f*w[12], h3 = 0.5f*w[13];
    const float base = phiL - h0 - h1 - h2 - h3;
#pragma unroll
    for (int r = 0; r < 16; ++r) {
      float ang = base;
      if (r & 8) ang += 2.f*h0;
      if (r & 4) ang += 2.f*h1;
      if (r & 2) ang += 2.f*h2;
      if (r & 1) ang += 2.f*h3;
      float sn, cn;
      __sincosf(ang, &sn, &cn);
      const float v = (r & 1) ? h[r >> 1].y : h[r >> 1].x;
      s[r] = (f2){ v * cn, v * sn };
    }
  }

  // T2: CNOT ring 1 fused into complex B->A transpose
#pragma unroll
  for (int r = 0; r < 16; ++r) stc[swz((r << 6) | lane)] = s[r];
#pragma unroll
  for (int r = 0; r < 16; ++r) s[r] = stc[swz(cnotL((lane << 4) | r))];

  // ===== combined RY: layer1 RY_b + layer2 RY_c (tab[60..69]), layout A =====
  cs = tab[66]; ry_reg<3>(s, cs.x, cs.y);
  cs = tab[67]; ry_reg<2>(s, cs.x, cs.y);
  cs = tab[68]; ry_reg<1>(s, cs.x, cs.y);
  cs = tab[69]; ry_reg<0>(s, cs.x, cs.y);
  cs = tab[64]; ry_shfl<2>(lane, s, cs.x, cs.y);
  cs = tab[65]; ry_shfl<1>(lane, s, cs.x, cs.y);

  // T3: complex A->B
#pragma unroll
  for (int r = 0; r < 16; ++r) stc[swz((lane << 4) | r)] = s[r];
#pragma unroll
  for (int r = 0; r < 16; ++r) s[r] = stc[swz((r << 6) | lane)];

  cs = tab[60]; ry_reg<3>(s, cs.x, cs.y);
  cs = tab[61]; ry_reg<2>(s, cs.x, cs.y);
  cs = tab[62]; ry_reg<1>(s, cs.x, cs.y);
  cs = tab[63]; ry_reg<0>(s, cs.x, cs.y);

  rz_apply(lane, w, 40, s);             // RZ layer 2

  // T4: CNOT ring 2 fused into complex B->A transpose
#pragma unroll
  for (int r = 0; r < 16; ++r) stc[swz((r << 6) | lane)] = s[r];
#pragma unroll
  for (int r = 0; r < 16; ++r) s[r] = stc[swz(cnotL((lane << 4) | r))];

  // ===== final RY round (w[50..59]) =====
  cs = tab[56]; ry_reg<3>(s, cs.x, cs.y);
  cs = tab[57]; ry_reg<2>(s, cs.x, cs.y);
  cs = tab[58]; ry_reg<1>(s, cs.x, cs.y);
  cs = tab[59]; ry_reg<0>(s, cs.x, cs.y);
  cs = tab[54]; ry_shfl<2>(lane, s, cs.x, cs.y);
  cs = tab[55]; ry_shfl<1>(lane, s, cs.x, cs.y);

  // T5: complex A->B
#pragma unroll
  for (int r = 0; r < 16; ++r) stc[swz((lane << 4) | r)] = s[r];
#pragma unroll
  for (int r = 0; r < 16; ++r) s[r] = stc[swz((r << 6) | lane)];

  cs = tab[50]; ry_reg<3>(s, cs.x, cs.y);
  cs = tab[51]; ry_reg<2>(s, cs.x, cs.y);
  cs = tab[52]; ry_reg<1>(s, cs.x, cs.y);
  cs = tab[53]; ry_reg<0>(s, cs.x, cs.y);

  // ===== expectation values (layout B) =====
  float acc[18];
#pragma unroll
  for (int k = 0; k < 12; ++k) acc[k] = 0.f;

  {
    float psum = 0.f;
    float a12 = 0.f, a13 = 0.f, a14 = 0.f, a15 = 0.f;
#pragma unroll
    for (int r = 0; r < 16; ++r) {
      const f2 t = s[r] * s[r];
      const float p = t.x + t.y;
      psum += p;
      a12 += (r & 8) ? -p : p;     // Z q0
      a13 += (r & 4) ? -p : p;     // Z q1
      a14 += (r & 2) ? -p : p;     // Z q2
      a15 += (r & 1) ? -p : p;     // Z q3
    }
    acc[12] = a12; acc[13] = a13; acc[14] = a14; acc[15] = a15;
    acc[16] = ((lane >> 5) & 1) ? -psum : psum;   // Z q4
    acc[17] = ((lane >> 4) & 1) ? -psum : psum;   // Z q5
  }

  xy_reg<3,0>(s, acc);
  xy_reg<2,1>(s, acc);
  xy_reg<1,2>(s, acc);
  xy_reg<0,3>(s, acc);
  xy_shfl<32,4>(lane, s, acc);
  xy_shfl<16,5>(lane, s, acc);

#pragma unroll
  for (int k = 0; k < 18; ++k) {
#pragma unroll
    for (int m = 32; m >= 1; m >>= 1) acc[k] += __shfl_xor(acc[k], m);
  }

  if (lane == 0) {
    float* ob = out + (size_t)b * 18;
#pragma unroll
    for (int k = 0; k < 18; ++k) ob[k] = acc[k] * inv_n2;
  }
}

extern "C" void kernel_launch(void* const* d_in, const int* in_sizes, int n_in,
                              void* d_out, int out_size, void* d_ws, size_t ws_size,
                              hipStream_t stream) {
  const float* x = (const float*)d_in[0];
  const float* w = (const float*)d_in[1];
  float* out = (float*)d_out;
  const int B = in_sizes[0] / DIN;
  const int grid = (B + 1) / 2;
  qae_kernel<<<dim3(grid), dim3(128), 0, stream>>>(x, w, out, B);
}

// Round 5
// 156.789 us; speedup vs baseline: 1.3094x; 1.1065x over previous
//
#include <hip/hip_runtime.h>

#define DIN 768

typedef float f2 __attribute__((ext_vector_type(2)));
typedef int i2v __attribute__((ext_vector_type(2)));

#if __has_builtin(__builtin_amdgcn_permlane32_swap)
#define HAVE_PL32 1
#endif
#if __has_builtin(__builtin_amdgcn_permlane16_swap)
#define HAVE_PL16 1
#endif

__device__ __forceinline__ int f2i(float v) { return __builtin_bit_cast(int, v); }
__device__ __forceinline__ float i2f(int v) { return __builtin_bit_cast(float, v); }

// DPP ctrl: quad_perm xor1 = [1,0,3,2] = 0xB1 ; xor2 = [2,3,0,1] = 0x4E ;
//           row_ror:4 = 0x124 ; row_ror:8 = 0x128  (row = 16 lanes)
template<int CTRL>
__device__ __forceinline__ float dppf(float v) {
  const int i = f2i(v);
  return i2f(__builtin_amdgcn_update_dpp(i, i, CTRL, 0xF, 0xF, true));
}
template<int CTRL>
__device__ __forceinline__ f2 dppf2(f2 v) {
  f2 r; r.x = dppf<CTRL>(v.x); r.y = dppf<CTRL>(v.y); return r;
}

// Full 64-lane sum, result in all lanes. Zero DS ops.
__device__ __forceinline__ float wsum(float v) {
  v += dppf<0xB1>(v);          // xor 1  -> group-of-2 sums
  v += dppf<0x4E>(v);          // xor 2  -> group-of-4 sums
  v += dppf<0x124>(v);         // ror 4  \ rotate-reduce -> row-of-16 sums
  v += dppf<0x128>(v);         // ror 8  /
#ifdef HAVE_PL16
  { i2v r = __builtin_amdgcn_permlane16_swap(f2i(v), f2i(v), false, false);
    v = i2f(r.x) + i2f(r.y); }
#else
  v += __shfl_xor(v, 16);
#endif
#ifdef HAVE_PL32
  { i2v r = __builtin_amdgcn_permlane32_swap(f2i(v), f2i(v), false, false);
    v = i2f(r.x) + i2f(r.y); }
#else
  v += __shfl_xor(v, 32);
#endif
  return v;
}

// xor-shuffle of an f2, VALU-only for masks 1,2,16,32.
template<int MASK>
__device__ __forceinline__ f2 shflx_f2(f2 v, int lane) {
  f2 r;
  if constexpr (MASK == 1) {
    r = dppf2<0xB1>(v);
  } else if constexpr (MASK == 2) {
    r = dppf2<0x4E>(v);
  } else if constexpr (MASK == 16) {
#ifdef HAVE_PL16
    const i2v a = __builtin_amdgcn_permlane16_swap(f2i(v.x), f2i(v.x), false, false);
    const i2v b = __builtin_amdgcn_permlane16_swap(f2i(v.y), f2i(v.y), false, false);
    const bool hi = (lane >> 4) & 1;
    r.x = hi ? i2f(a.x) : i2f(a.y);
    r.y = hi ? i2f(b.x) : i2f(b.y);
#else
    r.x = __shfl_xor(v.x, 16); r.y = __shfl_xor(v.y, 16);
#endif
  } else if constexpr (MASK == 32) {
#ifdef HAVE_PL32
    const i2v a = __builtin_amdgcn_permlane32_swap(f2i(v.x), f2i(v.x), false, false);
    const i2v b = __builtin_amdgcn_permlane32_swap(f2i(v.y), f2i(v.y), false, false);
    const bool lo = lane < 32;
    r.x = lo ? i2f(a.y) : i2f(a.x);
    r.y = lo ? i2f(b.y) : i2f(b.x);
#else
    r.x = __shfl_xor(v.x, 32); r.y = __shfl_xor(v.y, 32);
#endif
  } else {
    r.x = __shfl_xor(v.x, MASK); r.y = __shfl_xor(v.y, MASK);
  }
  return r;
}

// R2-proven swizzle for the 1024-cell complex f2 array (conflict-free incl. cnot gather)
__device__ __forceinline__ int swz(int i) { return i ^ ((i >> 4) & 31); }
__device__ __forceinline__ int swzr(int i) { return i ^ ((i >> 4) & 31); }

// Composite gather map of the CNOT ring CNOT(0,1)..CNOT(9,0): Final[i] = In[cnotL(i)]
__device__ __forceinline__ int cnotL(int i) {
  const int b9 = (i >> 9) & 1;
  const int b8 = (i >> 8) & 1;
  const int b0 = i & 1;
  return ((i ^ (i >> 1)) & 0xFF) | ((b8 ^ b9 ^ b0) << 8) | ((b9 ^ b0) << 9);
}

// ---------- real-state gates, packed: h[j] = (amp(2j), amp(2j+1)) ----------
template<int JB>
__device__ __forceinline__ void ry_real_pk(f2 (&h)[8], float c, float s) {
#pragma unroll
  for (int j = 0; j < 8; ++j) {
    if (!(j & (1 << JB))) {
      const int p = j | (1 << JB);
      const f2 a0 = h[j], a1 = h[p];
      h[j] = a0 * c - a1 * s;     // v_pk_mul + v_pk_fma
      h[p] = a1 * c + a0 * s;
    }
  }
}

__device__ __forceinline__ void ry_real_intra(f2 (&h)[8], float c, float s) {
  const f2 ssv = { -s, s };
#pragma unroll
  for (int j = 0; j < 8; ++j) {
    const f2 a = h[j];
    const f2 sw = { a.y, a.x };
    h[j] = sw * ssv + a * c;       // (c*x - s*y, s*x + c*y)
  }
}

template<int MASK>
__device__ __forceinline__ void ry_shfl_real_pk(int lane, f2 (&h)[8], float c, float s) {
  const float ss = (lane & MASK) ? s : -s;
#pragma unroll
  for (int j = 0; j < 8; ++j) {
    const f2 p = shflx_f2<MASK>(h[j], lane);
    h[j] = h[j] * c + p * ss;
  }
}

// ---------- complex (packed re/im) gates ----------
template<int RB>
__device__ __forceinline__ void ry_reg(f2 (&s)[16], float c, float sn) {
#pragma unroll
  for (int r = 0; r < 16; ++r) {
    if (!(r & (1 << RB))) {
      const int r1 = r | (1 << RB);
      const f2 a0 = s[r], a1 = s[r1];
      s[r]  = a0 * c - a1 * sn;
      s[r1] = a1 * c + a0 * sn;
    }
  }
}

template<int MASK>
__device__ __forceinline__ void ry_shfl(int lane, f2 (&s)[16], float c, float sn) {
  const float ss = (lane & MASK) ? sn : -sn;
#pragma unroll
  for (int r = 0; r < 16; ++r) {
    const f2 p = shflx_f2<MASK>(s[r], lane);
    s[r] = s[r] * c + p * ss;
  }
}

// RZ on all 10 qubits, layout B (i = (r<<6)|lane).
__device__ __forceinline__ void rz_apply(int lane, const float* __restrict__ w, int off, f2 (&s)[16]) {
  float phiL = 0.f;
#pragma unroll
  for (int j = 0; j < 6; ++j) {               // lane bit j <-> qubit 9-j
    const float h = 0.5f * w[off + 9 - j];
    phiL += ((lane >> j) & 1) ? h : -h;
  }
  const float h0 = 0.5f * w[off + 0];          // r bit 3 <-> qubit 0
  const float h1 = 0.5f * w[off + 1];
  const float h2 = 0.5f * w[off + 2];
  const float h3 = 0.5f * w[off + 3];
  const float base = phiL - h0 - h1 - h2 - h3;
#pragma unroll
  for (int r = 0; r < 16; ++r) {
    float ang = base;
    if (r & 8) ang += 2.f * h0;
    if (r & 4) ang += 2.f * h1;
    if (r & 2) ang += 2.f * h2;
    if (r & 1) ang += 2.f * h3;
    float sn, cn;
    __sincosf(ang, &sn, &cn);
    const f2 v = s[r];
    const f2 sw = { -v.y, v.x };               // i * v
    s[r] = v * cn + sw * sn;
  }
}

// ---------- expectation values (layout B) ----------
template<int RB, int Q>
__device__ __forceinline__ void xy_reg(const f2 (&s)[16], float (&acc)[18]) {
#pragma unroll
  for (int r = 0; r < 16; ++r) {
    if (!(r & (1 << RB))) {
      const int r1 = r | (1 << RB);
      const f2 t = s[r] * s[r1];
      acc[Q] = fmaf(2.f, t.x + t.y, acc[Q]);
      const f2 u = s[r] * (f2){ s[r1].y, s[r1].x };
      acc[Q + 6] = fmaf(2.f, u.x - u.y, acc[Q + 6]);
    }
  }
}

template<int MASK, int Q>
__device__ __forceinline__ void xy_shfl(int lane, const f2 (&s)[16], float (&acc)[18]) {
  const float sgn = (lane & MASK) ? -1.f : 1.f;
#pragma unroll
  for (int r = 0; r < 16; ++r) {
    const f2 p = shflx_f2<MASK>(s[r], lane);
    const f2 t = s[r] * p;
    acc[Q] += t.x + t.y;                       // pair double-counted -> net 2x
    const f2 u = s[r] * (f2){ p.y, p.x };
    acc[Q + 6] += sgn * (u.x - u.y);
  }
}

__global__ __launch_bounds__(128) void qae_kernel(const float* __restrict__ x,
                                                  const float* __restrict__ w,
                                                  float* __restrict__ out, int Btot) {
  __shared__ f2 st_all[2 * 1024];       // wave-private 8KB regions
  __shared__ float2 tab[70];            // (cos, sin) half-angles; [60..69] folded round

  const int tid  = threadIdx.x;
  const int lane = tid & 63;
  const int wid  = tid >> 6;
  const int b    = blockIdx.x * 2 + wid;
  f2* stc = st_all + (wid << 10);       // 1024 f2 cells, this wave's region

  if (tid < 60) {                       // all in wave 0
    float s, c;
    __sincosf(0.5f * w[tid], &s, &c);
    tab[tid] = make_float2(c, s);
  }
  if (tid < 10) {                       // RY_b(layer1) + RY_c(layer2) folded
    float s, c;
    __sincosf(0.5f * (w[20 + tid] + w[30 + tid]), &s, &c);
    tab[60 + tid] = make_float2(c, s);
  }
  __syncthreads();                      // the ONLY block-wide barrier
  if (b >= Btot) return;

  // Load row, layout A packed: h[j] = (x[lane*16+2j], x[lane*16+2j+1]); i >= 768 zero.
  f2 h[8];
  float sumsq = 0.f;
  const float* xb = x + (size_t)b * DIN;
#pragma unroll
  for (int t = 0; t < 4; ++t) {
    const int idx = lane * 16 + 4 * t;
    float4 v = make_float4(0.f, 0.f, 0.f, 0.f);
    if (idx < DIN) v = *reinterpret_cast<const float4*>(xb + idx);
    h[2*t]   = (f2){ v.x, v.y };
    h[2*t+1] = (f2){ v.z, v.w };
    sumsq += v.x*v.x; sumsq += v.y*v.y; sumsq += v.z*v.z; sumsq += v.w*v.w;
  }
  sumsq = wsum(sumsq);
  const float inv_n2 = 1.f / fmaxf(sumsq, 1e-16f);  // deferred normalization

  float2 cs;
  // ===== layer 1 RY round (w[0..9]) — REAL state, layout A =====
  // A: j bit2..0 <-> q6,q7,q8 ; intra <-> q9 ; lane bit1,bit0 <-> q4,q5
  cs = tab[6]; ry_real_pk<2>(h, cs.x, cs.y);
  cs = tab[7]; ry_real_pk<1>(h, cs.x, cs.y);
  cs = tab[8]; ry_real_pk<0>(h, cs.x, cs.y);
  cs = tab[9]; ry_real_intra(h, cs.x, cs.y);
  cs = tab[4]; ry_shfl_real_pk<2>(lane, h, cs.x, cs.y);
  cs = tab[5]; ry_shfl_real_pk<1>(lane, h, cs.x, cs.y);

  { // T1: real A->B transpose (512-cell f2 space)
    f2* st2 = stc;
#pragma unroll
    for (int j = 0; j < 8; ++j) st2[swzr((lane << 3) | j)] = h[j];
    const float* st1 = reinterpret_cast<const float*>(st2);
#pragma unroll
    for (int j = 0; j < 8; ++j) {
      const int i2a = ((2*j)   << 5) | (lane >> 1);
      const int i2b = ((2*j+1) << 5) | (lane >> 1);
      h[j].x = st1[swzr(i2a) * 2 + (lane & 1)];
      h[j].y = st1[swzr(i2b) * 2 + (lane & 1)];
    }
  }
  // B: j bit2..0 <-> q0,q1,q2 ; intra <-> q3
  cs = tab[0]; ry_real_pk<2>(h, cs.x, cs.y);
  cs = tab[1]; ry_real_pk<1>(h, cs.x, cs.y);
  cs = tab[2]; ry_real_pk<0>(h, cs.x, cs.y);
  cs = tab[3]; ry_real_intra(h, cs.x, cs.y);

  // RZ layer 1 (w[10..19]): real -> complex packed
  f2 s[16];
  {
    float phiL = 0.f;
#pragma unroll
    for (int j = 0; j < 6; ++j) {
      const float hh = 0.5f * w[10 + 9 - j];
      phiL += ((lane >> j) & 1) ? hh : -hh;
    }
    const float h0 = 0.5f*w[10], h1 = 0.5f*w[11], h2 = 0.5f*w[12], h3 = 0.5f*w[13];
    const float base = phiL - h0 - h1 - h2 - h3;
#pragma unroll
    for (int r = 0; r < 16; ++r) {
      float ang = base;
      if (r & 8) ang += 2.f*h0;
      if (r & 4) ang += 2.f*h1;
      if (r & 2) ang += 2.f*h2;
      if (r & 1) ang += 2.f*h3;
      float sn, cn;
      __sincosf(ang, &sn, &cn);
      const float v = (r & 1) ? h[r >> 1].y : h[r >> 1].x;
      s[r] = (f2){ v * cn, v * sn };
    }
  }

  // T2: CNOT ring 1 fused into complex B->A transpose
#pragma unroll
  for (int r = 0; r < 16; ++r) stc[swz((r << 6) | lane)] = s[r];
#pragma unroll
  for (int r = 0; r < 16; ++r) s[r] = stc[swz(cnotL((lane << 4) | r))];

  // ===== combined RY: layer1 RY_b + layer2 RY_c (tab[60..69]), layout A =====
  cs = tab[66]; ry_reg<3>(s, cs.x, cs.y);
  cs = tab[67]; ry_reg<2>(s, cs.x, cs.y);
  cs = tab[68]; ry_reg<1>(s, cs.x, cs.y);
  cs = tab[69]; ry_reg<0>(s, cs.x, cs.y);
  cs = tab[64]; ry_shfl<2>(lane, s, cs.x, cs.y);
  cs = tab[65]; ry_shfl<1>(lane, s, cs.x, cs.y);

  // T3: complex A->B
#pragma unroll
  for (int r = 0; r < 16; ++r) stc[swz((lane << 4) | r)] = s[r];
#pragma unroll
  for (int r = 0; r < 16; ++r) s[r] = stc[swz((r << 6) | lane)];

  cs = tab[60]; ry_reg<3>(s, cs.x, cs.y);
  cs = tab[61]; ry_reg<2>(s, cs.x, cs.y);
  cs = tab[62]; ry_reg<1>(s, cs.x, cs.y);
  cs = tab[63]; ry_reg<0>(s, cs.x, cs.y);

  rz_apply(lane, w, 40, s);             // RZ layer 2

  // T4: CNOT ring 2 fused into complex B->A transpose
#pragma unroll
  for (int r = 0; r < 16; ++r) stc[swz((r << 6) | lane)] = s[r];
#pragma unroll
  for (int r = 0; r < 16; ++r) s[r] = stc[swz(cnotL((lane << 4) | r))];

  // ===== final RY round (w[50..59]) =====
  cs = tab[56]; ry_reg<3>(s, cs.x, cs.y);
  cs = tab[57]; ry_reg<2>(s, cs.x, cs.y);
  cs = tab[58]; ry_reg<1>(s, cs.x, cs.y);
  cs = tab[59]; ry_reg<0>(s, cs.x, cs.y);
  cs = tab[54]; ry_shfl<2>(lane, s, cs.x, cs.y);
  cs = tab[55]; ry_shfl<1>(lane, s, cs.x, cs.y);

  // T5: complex A->B
#pragma unroll
  for (int r = 0; r < 16; ++r) stc[swz((lane << 4) | r)] = s[r];
#pragma unroll
  for (int r = 0; r < 16; ++r) s[r] = stc[swz((r << 6) | lane)];

  cs = tab[50]; ry_reg<3>(s, cs.x, cs.y);
  cs = tab[51]; ry_reg<2>(s, cs.x, cs.y);
  cs = tab[52]; ry_reg<1>(s, cs.x, cs.y);
  cs = tab[53]; ry_reg<0>(s, cs.x, cs.y);

  // ===== expectation values (layout B) =====
  float acc[18];
#pragma unroll
  for (int k = 0; k < 12; ++k) acc[k] = 0.f;

  {
    float psum = 0.f;
    float a12 = 0.f, a13 = 0.f, a14 = 0.f, a15 = 0.f;
#pragma unroll
    for (int r = 0; r < 16; ++r) {
      const f2 t = s[r] * s[r];
      const float p = t.x + t.y;
      psum += p;
      a12 += (r & 8) ? -p : p;     // Z q0
      a13 += (r & 4) ? -p : p;     // Z q1
      a14 += (r & 2) ? -p : p;     // Z q2
      a15 += (r & 1) ? -p : p;     // Z q3
    }
    acc[12] = a12; acc[13] = a13; acc[14] = a14; acc[15] = a15;
    acc[16] = ((lane >> 5) & 1) ? -psum : psum;   // Z q4
    acc[17] = ((lane >> 4) & 1) ? -psum : psum;   // Z q5
  }

  xy_reg<3,0>(s, acc);
  xy_reg<2,1>(s, acc);
  xy_reg<1,2>(s, acc);
  xy_reg<0,3>(s, acc);
  xy_shfl<32,4>(lane, s, acc);
  xy_shfl<16,5>(lane, s, acc);

#pragma unroll
  for (int k = 0; k < 18; ++k) acc[k] = wsum(acc[k]);   // VALU-only reduce

  if (lane == 0) {
    float* ob = out + (size_t)b * 18;
#pragma unroll
    for (int k = 0; k < 18; ++k) ob[k] = acc[k] * inv_n2;
  }
}

extern "C" void kernel_launch(void* const* d_in, const int* in_sizes, int n_in,
                              void* d_out, int out_size, void* d_ws, size_t ws_size,
                              hipStream_t stream) {
  const float* x = (const float*)d_in[0];
  const float* w = (const float*)d_in[1];
  float* out = (float*)d_out;
  const int B = in_sizes[0] / DIN;
  const int grid = (B + 1) / 2;
  qae_kernel<<<dim3(grid), dim3(128), 0, stream>>>(x, w, out, B);
}

// Round 6
// 143.308 us; speedup vs baseline: 1.4326x; 1.0941x over previous
//
#include <hip/hip_runtime.h>

#define DIN 768

typedef float f2 __attribute__((ext_vector_type(2)));
typedef int i2v __attribute__((ext_vector_type(2)));

#if __has_builtin(__builtin_amdgcn_permlane32_swap)
#define HAVE_PL32 1
#endif
#if __has_builtin(__builtin_amdgcn_permlane16_swap)
#define HAVE_PL16 1
#endif

__device__ __forceinline__ int f2i(float v) { return __builtin_bit_cast(int, v); }
__device__ __forceinline__ float i2f(int v) { return __builtin_bit_cast(float, v); }

// DPP ctrl: quad_perm xor1 = [1,0,3,2] = 0xB1 ; xor2 = [2,3,0,1] = 0x4E ;
//           row_ror:4 = 0x124 ; row_ror:8 = 0x128  (row = 16 lanes)
template<int CTRL>
__device__ __forceinline__ float dppf(float v) {
  const int i = f2i(v);
  return i2f(__builtin_amdgcn_update_dpp(i, i, CTRL, 0xF, 0xF, true));
}
template<int CTRL>
__device__ __forceinline__ f2 dppf2(f2 v) {
  f2 r; r.x = dppf<CTRL>(v.x); r.y = dppf<CTRL>(v.y); return r;
}

// Full 64-lane sum, result in all lanes. Zero DS ops.
__device__ __forceinline__ float wsum(float v) {
  v += dppf<0xB1>(v);          // xor 1  -> group-of-2 sums
  v += dppf<0x4E>(v);          // xor 2  -> group-of-4 sums
  v += dppf<0x124>(v);         // ror 4  \ rotate-reduce -> row-of-16 sums
  v += dppf<0x128>(v);         // ror 8  /
#ifdef HAVE_PL16
  { i2v r = __builtin_amdgcn_permlane16_swap(f2i(v), f2i(v), false, false);
    v = i2f(r.x) + i2f(r.y); }
#else
  v += __shfl_xor(v, 16);
#endif
#ifdef HAVE_PL32
  { i2v r = __builtin_amdgcn_permlane32_swap(f2i(v), f2i(v), false, false);
    v = i2f(r.x) + i2f(r.y); }
#else
  v += __shfl_xor(v, 32);
#endif
  return v;
}

// xor-shuffle of an f2, VALU-only for masks 1,2,16,32.
template<int MASK>
__device__ __forceinline__ f2 shflx_f2(f2 v, int lane) {
  f2 r;
  if constexpr (MASK == 1) {
    r = dppf2<0xB1>(v);
  } else if constexpr (MASK == 2) {
    r = dppf2<0x4E>(v);
  } else if constexpr (MASK == 16) {
#ifdef HAVE_PL16
    const i2v a = __builtin_amdgcn_permlane16_swap(f2i(v.x), f2i(v.x), false, false);
    const i2v b = __builtin_amdgcn_permlane16_swap(f2i(v.y), f2i(v.y), false, false);
    const bool hi = (lane >> 4) & 1;
    r.x = hi ? i2f(a.x) : i2f(a.y);
    r.y = hi ? i2f(b.x) : i2f(b.y);
#else
    r.x = __shfl_xor(v.x, 16); r.y = __shfl_xor(v.y, 16);
#endif
  } else if constexpr (MASK == 32) {
#ifdef HAVE_PL32
    const i2v a = __builtin_amdgcn_permlane32_swap(f2i(v.x), f2i(v.x), false, false);
    const i2v b = __builtin_amdgcn_permlane32_swap(f2i(v.y), f2i(v.y), false, false);
    const bool lo = lane < 32;
    r.x = lo ? i2f(a.y) : i2f(a.x);
    r.y = lo ? i2f(b.y) : i2f(b.x);
#else
    r.x = __shfl_xor(v.x, 32); r.y = __shfl_xor(v.y, 32);
#endif
  } else {
    r.x = __shfl_xor(v.x, MASK); r.y = __shfl_xor(v.y, MASK);
  }
  return r;
}

// swizzle for LDS transposes (conflict-free on A/B patterns; cnot gather measured cheap)
__device__ __forceinline__ int swz(int i) { return i ^ ((i >> 4) & 31); }
__device__ __forceinline__ int swzr(int i) { return i ^ ((i >> 4) & 31); }

// Composite gather map of the CNOT ring CNOT(0,1)..CNOT(9,0): Final[i] = In[cnotL(i)]
__device__ __forceinline__ int cnotL(int i) {
  const int b9 = (i >> 9) & 1;
  const int b8 = (i >> 8) & 1;
  const int b0 = i & 1;
  return ((i ^ (i >> 1)) & 0xFF) | ((b8 ^ b9 ^ b0) << 8) | ((b9 ^ b0) << 9);
}

// ---------- real-state gates, packed: h[j] = (amp(2j), amp(2j+1)) ----------
template<int JB>
__device__ __forceinline__ void ry_real_pk(f2 (&h)[8], float c, float s) {
#pragma unroll
  for (int j = 0; j < 8; ++j) {
    if (!(j & (1 << JB))) {
      const int p = j | (1 << JB);
      const f2 a0 = h[j], a1 = h[p];
      h[j] = a0 * c - a1 * s;     // v_pk_mul + v_pk_fma
      h[p] = a1 * c + a0 * s;
    }
  }
}

__device__ __forceinline__ void ry_real_intra(f2 (&h)[8], float c, float s) {
  const f2 ssv = { -s, s };
#pragma unroll
  for (int j = 0; j < 8; ++j) {
    const f2 a = h[j];
    const f2 sw = { a.y, a.x };
    h[j] = sw * ssv + a * c;       // (c*x - s*y, s*x + c*y)
  }
}

template<int MASK>
__device__ __forceinline__ void ry_shfl_real_pk(int lane, f2 (&h)[8], float c, float s) {
  const float ss = (lane & MASK) ? s : -s;
#pragma unroll
  for (int j = 0; j < 8; ++j) {
    const f2 p = shflx_f2<MASK>(h[j], lane);
    h[j] = h[j] * c + p * ss;
  }
}

// ---------- complex (packed re/im) gates ----------
template<int RB>
__device__ __forceinline__ void ry_reg(f2 (&s)[16], float c, float sn) {
#pragma unroll
  for (int r = 0; r < 16; ++r) {
    if (!(r & (1 << RB))) {
      const int r1 = r | (1 << RB);
      const f2 a0 = s[r], a1 = s[r1];
      s[r]  = a0 * c - a1 * sn;
      s[r1] = a1 * c + a0 * sn;
    }
  }
}

template<int MASK>
__device__ __forceinline__ void ry_shfl(int lane, f2 (&s)[16], float c, float sn) {
  const float ss = (lane & MASK) ? sn : -sn;
#pragma unroll
  for (int r = 0; r < 16; ++r) {
    const f2 p = shflx_f2<MASK>(s[r], lane);
    s[r] = s[r] * c + p * ss;
  }
}

// RZ on all 10 qubits, layout B (i = (r<<6)|lane).
__device__ __forceinline__ void rz_apply(int lane, const float* __restrict__ w, int off, f2 (&s)[16]) {
  float phiL = 0.f;
#pragma unroll
  for (int j = 0; j < 6; ++j) {               // lane bit j <-> qubit 9-j
    const float h = 0.5f * w[off + 9 - j];
    phiL += ((lane >> j) & 1) ? h : -h;
  }
  const float h0 = 0.5f * w[off + 0];          // r bit 3 <-> qubit 0
  const float h1 = 0.5f * w[off + 1];
  const float h2 = 0.5f * w[off + 2];
  const float h3 = 0.5f * w[off + 3];
  const float base = phiL - h0 - h1 - h2 - h3;
#pragma unroll
  for (int r = 0; r < 16; ++r) {
    float ang = base;
    if (r & 8) ang += 2.f * h0;
    if (r & 4) ang += 2.f * h1;
    if (r & 2) ang += 2.f * h2;
    if (r & 1) ang += 2.f * h3;
    float sn, cn;
    __sincosf(ang, &sn, &cn);
    const f2 v = s[r];
    const f2 sw = { -v.y, v.x };               // i * v
    s[r] = v * cn + sw * sn;
  }
}

// ---------- expectation values (layout B) ----------
template<int RB, int Q>
__device__ __forceinline__ void xy_reg(const f2 (&s)[16], float (&acc)[18]) {
#pragma unroll
  for (int r = 0; r < 16; ++r) {
    if (!(r & (1 << RB))) {
      const int r1 = r | (1 << RB);
      const f2 t = s[r] * s[r1];
      acc[Q] = fmaf(2.f, t.x + t.y, acc[Q]);
      const f2 u = s[r] * (f2){ s[r1].y, s[r1].x };
      acc[Q + 6] = fmaf(2.f, u.x - u.y, acc[Q + 6]);
    }
  }
}

template<int MASK, int Q>
__device__ __forceinline__ void xy_shfl(int lane, const f2 (&s)[16], float (&acc)[18]) {
  const float sgn = (lane & MASK) ? -1.f : 1.f;
#pragma unroll
  for (int r = 0; r < 16; ++r) {
    const f2 p = shflx_f2<MASK>(s[r], lane);
    const f2 t = s[r] * p;
    acc[Q] += t.x + t.y;                       // pair double-counted -> net 2x
    const f2 u = s[r] * (f2){ p.y, p.x };
    acc[Q + 6] += sgn * (u.x - u.y);
  }
}

__global__ __launch_bounds__(128) void qae_kernel(const float* __restrict__ x,
                                                  const float* __restrict__ w,
                                                  float* __restrict__ out, int Btot) {
  __shared__ f2 st_all[2 * 1024];       // wave-private 8KB regions
  __shared__ float2 tab[70];            // [0..49] half-angle gates; [50..55] FULL-angle
                                        // (cos,sin) of w[50+q] for the Heisenberg output
                                        // transform; [60..69] folded RY round
  const int tid  = threadIdx.x;
  const int lane = tid & 63;
  const int wid  = tid >> 6;
  const int b    = blockIdx.x * 2 + wid;
  f2* stc = st_all + (wid << 10);       // 1024 f2 cells, this wave's region

  if (tid < 50) {                       // half-angle gate table
    float s, c;
    __sincosf(0.5f * w[tid], &s, &c);
    tab[tid] = make_float2(c, s);
  } else if (tid < 56) {                // FULL angle: final-round observable transform
    float s, c;
    __sincosf(w[tid], &s, &c);
    tab[tid] = make_float2(c, s);
  }
  if (tid < 10) {                       // RY_b(layer1) + RY_c(layer2) folded
    float s, c;
    __sincosf(0.5f * (w[20 + tid] + w[30 + tid]), &s, &c);
    tab[60 + tid] = make_float2(c, s);
  }
  __syncthreads();                      // the ONLY block-wide barrier
  if (b >= Btot) return;

  // Load row, layout A packed: h[j] = (x[lane*16+2j], x[lane*16+2j+1]); i >= 768 zero.
  f2 h[8];
  float sumsq = 0.f;
  const float* xb = x + (size_t)b * DIN;
#pragma unroll
  for (int t = 0; t < 4; ++t) {
    const int idx = lane * 16 + 4 * t;
    float4 v = make_float4(0.f, 0.f, 0.f, 0.f);
    if (idx < DIN) v = *reinterpret_cast<const float4*>(xb + idx);
    h[2*t]   = (f2){ v.x, v.y };
    h[2*t+1] = (f2){ v.z, v.w };
    sumsq += v.x*v.x; sumsq += v.y*v.y; sumsq += v.z*v.z; sumsq += v.w*v.w;
  }
  sumsq = wsum(sumsq);
  const float inv_n2 = 1.f / fmaxf(sumsq, 1e-16f);  // deferred normalization

  float2 cs;
  // ===== layer 1 RY round (w[0..9]) — REAL state, layout A =====
  // A: j bit2..0 <-> q6,q7,q8 ; intra <-> q9 ; lane bit1,bit0 <-> q4,q5
  cs = tab[6]; ry_real_pk<2>(h, cs.x, cs.y);
  cs = tab[7]; ry_real_pk<1>(h, cs.x, cs.y);
  cs = tab[8]; ry_real_pk<0>(h, cs.x, cs.y);
  cs = tab[9]; ry_real_intra(h, cs.x, cs.y);
  cs = tab[4]; ry_shfl_real_pk<2>(lane, h, cs.x, cs.y);
  cs = tab[5]; ry_shfl_real_pk<1>(lane, h, cs.x, cs.y);

  { // T1: real A->B transpose (512-cell f2 space)
    f2* st2 = stc;
#pragma unroll
    for (int j = 0; j < 8; ++j) st2[swzr((lane << 3) | j)] = h[j];
    const float* st1 = reinterpret_cast<const float*>(st2);
#pragma unroll
    for (int j = 0; j < 8; ++j) {
      const int i2a = ((2*j)   << 5) | (lane >> 1);
      const int i2b = ((2*j+1) << 5) | (lane >> 1);
      h[j].x = st1[swzr(i2a) * 2 + (lane & 1)];
      h[j].y = st1[swzr(i2b) * 2 + (lane & 1)];
    }
  }
  // B: j bit2..0 <-> q0,q1,q2 ; intra <-> q3
  cs = tab[0]; ry_real_pk<2>(h, cs.x, cs.y);
  cs = tab[1]; ry_real_pk<1>(h, cs.x, cs.y);
  cs = tab[2]; ry_real_pk<0>(h, cs.x, cs.y);
  cs = tab[3]; ry_real_intra(h, cs.x, cs.y);

  // RZ layer 1 (w[10..19]): real -> complex packed
  f2 s[16];
  {
    float phiL = 0.f;
#pragma unroll
    for (int j = 0; j < 6; ++j) {
      const float hh = 0.5f * w[10 + 9 - j];
      phiL += ((lane >> j) & 1) ? hh : -hh;
    }
    const float h0 = 0.5f*w[10], h1 = 0.5f*w[11], h2 = 0.5f*w[12], h3 = 0.5f*w[13];
    const float base = phiL - h0 - h1 - h2 - h3;
#pragma unroll
    for (int r = 0; r < 16; ++r) {
      float ang = base;
      if (r & 8) ang += 2.f*h0;
      if (r & 4) ang += 2.f*h1;
      if (r & 2) ang += 2.f*h2;
      if (r & 1) ang += 2.f*h3;
      float sn, cn;
      __sincosf(ang, &sn, &cn);
      const float v = (r & 1) ? h[r >> 1].y : h[r >> 1].x;
      s[r] = (f2){ v * cn, v * sn };
    }
  }

  // T2: CNOT ring 1 fused into complex B->A transpose
#pragma unroll
  for (int r = 0; r < 16; ++r) stc[swz((r << 6) | lane)] = s[r];
#pragma unroll
  for (int r = 0; r < 16; ++r) s[r] = stc[swz(cnotL((lane << 4) | r))];

  // ===== combined RY: layer1 RY_b + layer2 RY_c (tab[60..69]), layout A =====
  cs = tab[66]; ry_reg<3>(s, cs.x, cs.y);
  cs = tab[67]; ry_reg<2>(s, cs.x, cs.y);
  cs = tab[68]; ry_reg<1>(s, cs.x, cs.y);
  cs = tab[69]; ry_reg<0>(s, cs.x, cs.y);
  cs = tab[64]; ry_shfl<2>(lane, s, cs.x, cs.y);
  cs = tab[65]; ry_shfl<1>(lane, s, cs.x, cs.y);

  // T3: complex A->B
#pragma unroll
  for (int r = 0; r < 16; ++r) stc[swz((lane << 4) | r)] = s[r];
#pragma unroll
  for (int r = 0; r < 16; ++r) s[r] = stc[swz((r << 6) | lane)];

  cs = tab[60]; ry_reg<3>(s, cs.x, cs.y);
  cs = tab[61]; ry_reg<2>(s, cs.x, cs.y);
  cs = tab[62]; ry_reg<1>(s, cs.x, cs.y);
  cs = tab[63]; ry_reg<0>(s, cs.x, cs.y);

  rz_apply(lane, w, 40, s);             // RZ layer 2

  // T4: CNOT ring 2, gather read DIRECTLY into layout B (final RY round is
  // algebraically folded into the output transform, so no more gates follow
  // and T5 is eliminated).
#pragma unroll
  for (int r = 0; r < 16; ++r) stc[swz((r << 6) | lane)] = s[r];
#pragma unroll
  for (int r = 0; r < 16; ++r) s[r] = stc[swz(cnotL((r << 6) | lane))];

  // ===== expectation values (layout B, pre-final-round state) =====
  float acc[18];
#pragma unroll
  for (int k = 0; k < 12; ++k) acc[k] = 0.f;

  {
    float psum = 0.f;
    float a12 = 0.f, a13 = 0.f, a14 = 0.f, a15 = 0.f;
#pragma unroll
    for (int r = 0; r < 16; ++r) {
      const f2 t = s[r] * s[r];
      const float p = t.x + t.y;
      psum += p;
      a12 += (r & 8) ? -p : p;     // Z q0
      a13 += (r & 4) ? -p : p;     // Z q1
      a14 += (r & 2) ? -p : p;     // Z q2
      a15 += (r & 1) ? -p : p;     // Z q3
    }
    acc[12] = a12; acc[13] = a13; acc[14] = a14; acc[15] = a15;
    acc[16] = ((lane >> 5) & 1) ? -psum : psum;   // Z q4
    acc[17] = ((lane >> 4) & 1) ? -psum : psum;   // Z q5
  }

  xy_reg<3,0>(s, acc);
  xy_reg<2,1>(s, acc);
  xy_reg<1,2>(s, acc);
  xy_reg<0,3>(s, acc);
  xy_shfl<32,4>(lane, s, acc);
  xy_shfl<16,5>(lane, s, acc);

#pragma unroll
  for (int k = 0; k < 18; ++k) acc[k] = wsum(acc[k]);   // VALU-only reduce

  if (lane == 0) {
    // Heisenberg transform of the dropped final RY round (full angles w[50+q]):
    // X' = c*X + s*Z ; Y' = Y ; Z' = c*Z - s*X
    float* ob = out + (size_t)b * 18;
#pragma unroll
    for (int q = 0; q < 6; ++q) {
      const float2 fa = tab[50 + q];
      const float X = acc[q], Z = acc[12 + q];
      ob[q]      = (fa.x * X + fa.y * Z) * inv_n2;
      ob[6 + q]  = acc[6 + q] * inv_n2;
      ob[12 + q] = (fa.x * Z - fa.y * X) * inv_n2;
    }
  }
}

extern "C" void kernel_launch(void* const* d_in, const int* in_sizes, int n_in,
                              void* d_out, int out_size, void* d_ws, size_t ws_size,
                              hipStream_t stream) {
  const float* x = (const float*)d_in[0];
  const float* w = (const float*)d_in[1];
  float* out = (float*)d_out;
  const int B = in_sizes[0] / DIN;
  const int grid = (B + 1) / 2;
  qae_kernel<<<dim3(grid), dim3(128), 0, stream>>>(x, w, out, B);
}

// Round 7
// 124.718 us; speedup vs baseline: 1.6461x; 1.1491x over previous
//
#include <hip/hip_runtime.h>

#define DIN 768

typedef float f2 __attribute__((ext_vector_type(2)));
typedef int i2v __attribute__((ext_vector_type(2)));

#if __has_builtin(__builtin_amdgcn_permlane32_swap)
#define HAVE_PL32 1
#endif
#if __has_builtin(__builtin_amdgcn_permlane16_swap)
#define HAVE_PL16 1
#endif

__device__ __forceinline__ int f2i(float v) { return __builtin_bit_cast(int, v); }
__device__ __forceinline__ float i2f(int v) { return __builtin_bit_cast(float, v); }

// DPP ctrl: quad_perm xor1 = 0xB1 ; xor2 = 0x4E ; row_ror:4 = 0x124 ; row_ror:8 = 0x128
template<int CTRL>
__device__ __forceinline__ float dppf(float v) {
  const int i = f2i(v);
  return i2f(__builtin_amdgcn_update_dpp(i, i, CTRL, 0xF, 0xF, true));
}
template<int CTRL>
__device__ __forceinline__ f2 dppf2(f2 v) {
  f2 r; r.x = dppf<CTRL>(v.x); r.y = dppf<CTRL>(v.y); return r;
}

// Full 64-lane sum of both f2 components (2 rows at once). Zero DS ops.
__device__ __forceinline__ f2 wsum2(f2 v) {
  v += dppf2<0xB1>(v);
  v += dppf2<0x4E>(v);
  v += dppf2<0x124>(v);
  v += dppf2<0x128>(v);
#ifdef HAVE_PL16
  { i2v rx = __builtin_amdgcn_permlane16_swap(f2i(v.x), f2i(v.x), false, false);
    i2v ry = __builtin_amdgcn_permlane16_swap(f2i(v.y), f2i(v.y), false, false);
    v.x = i2f(rx.x) + i2f(rx.y);
    v.y = i2f(ry.x) + i2f(ry.y); }
#else
  v.x += __shfl_xor(v.x, 16); v.y += __shfl_xor(v.y, 16);
#endif
#ifdef HAVE_PL32
  { i2v rx = __builtin_amdgcn_permlane32_swap(f2i(v.x), f2i(v.x), false, false);
    i2v ry = __builtin_amdgcn_permlane32_swap(f2i(v.y), f2i(v.y), false, false);
    v.x = i2f(rx.x) + i2f(rx.y);
    v.y = i2f(ry.x) + i2f(ry.y); }
#else
  v.x += __shfl_xor(v.x, 32); v.y += __shfl_xor(v.y, 32);
#endif
  return v;
}

// xor-shuffle of an f2, VALU-only for masks 1,2,16,32.
template<int MASK>
__device__ __forceinline__ f2 shflx_f2(f2 v, int lane) {
  f2 r;
  if constexpr (MASK == 1) {
    r = dppf2<0xB1>(v);
  } else if constexpr (MASK == 2) {
    r = dppf2<0x4E>(v);
  } else if constexpr (MASK == 16) {
#ifdef HAVE_PL16
    const i2v a = __builtin_amdgcn_permlane16_swap(f2i(v.x), f2i(v.x), false, false);
    const i2v b = __builtin_amdgcn_permlane16_swap(f2i(v.y), f2i(v.y), false, false);
    const bool hi = (lane >> 4) & 1;
    r.x = hi ? i2f(a.x) : i2f(a.y);
    r.y = hi ? i2f(b.x) : i2f(b.y);
#else
    r.x = __shfl_xor(v.x, 16); r.y = __shfl_xor(v.y, 16);
#endif
  } else if constexpr (MASK == 32) {
#ifdef HAVE_PL32
    const i2v a = __builtin_amdgcn_permlane32_swap(f2i(v.x), f2i(v.x), false, false);
    const i2v b = __builtin_amdgcn_permlane32_swap(f2i(v.y), f2i(v.y), false, false);
    const bool lo = lane < 32;
    r.x = lo ? i2f(a.y) : i2f(a.x);
    r.y = lo ? i2f(b.y) : i2f(b.x);
#else
    r.x = __shfl_xor(v.x, 32); r.y = __shfl_xor(v.y, 32);
#endif
  } else {
    r.x = __shfl_xor(v.x, MASK); r.y = __shfl_xor(v.y, MASK);
  }
  return r;
}

__device__ __forceinline__ int swz(int i) { return i ^ ((i >> 4) & 31); }

// Composite gather map of the CNOT ring CNOT(0,1)..CNOT(9,0): Final[i] = In[cnotL(i)]
__device__ __forceinline__ int cnotL(int i) {
  const int b9 = (i >> 9) & 1;
  const int b8 = (i >> 8) & 1;
  const int b0 = i & 1;
  return ((i ^ (i >> 1)) & 0xFF) | ((b8 ^ b9 ^ b0) << 8) | ((b9 ^ b0) << 9);
}

// RY on a 16-reg component array (rows packed in f2). Real 2x2 acts per component.
template<int RB>
__device__ __forceinline__ void ry1(f2 (&a)[16], float c, float s) {
#pragma unroll
  for (int r = 0; r < 16; ++r) {
    if (!(r & (1 << RB))) {
      const int p = r | (1 << RB);
      const f2 a0 = a[r], a1 = a[p];
      a[r] = a0 * c - a1 * s;
      a[p] = a1 * c + a0 * s;
    }
  }
}
template<int RB>
__device__ __forceinline__ void ry2(f2 (&re)[16], f2 (&im)[16], float c, float s) {
  ry1<RB>(re, c, s);
  ry1<RB>(im, c, s);
}
template<int MASK>
__device__ __forceinline__ void ry1_shfl(int lane, f2 (&a)[16], float c, float s) {
  const float ss = (lane & MASK) ? s : -s;
#pragma unroll
  for (int r = 0; r < 16; ++r) {
    const f2 p = shflx_f2<MASK>(a[r], lane);
    a[r] = a[r] * c + p * ss;
  }
}

// X/Y accumulate, register-pair qubit (each unordered pair once -> fac 2 at output)
template<int RB>
__device__ __forceinline__ void xyr(const f2 (&re)[16], const f2 (&im)[16], f2& aX, f2& aY) {
#pragma unroll
  for (int r = 0; r < 16; ++r) {
    if (!(r & (1 << RB))) {
      const int p = r | (1 << RB);
      aX += re[r] * re[p] + im[r] * im[p];
      aY += re[r] * im[p] - im[r] * re[p];
    }
  }
}
// X/Y accumulate, lane-bit qubit (each ordered pair counted -> net 2x already)
template<int MASK>
__device__ __forceinline__ void xys(int lane, const f2 (&re)[16], const f2 (&im)[16], f2& aX, f2& aY) {
  const float sgn = (lane & MASK) ? -1.f : 1.f;
#pragma unroll
  for (int r = 0; r < 16; ++r) {
    const f2 pr = shflx_f2<MASK>(re[r], lane);
    const f2 pi = shflx_f2<MASK>(im[r], lane);
    aX += re[r] * pr + im[r] * pi;
    aY += (re[r] * pi - im[r] * pr) * sgn;
  }
}

// ---------------- prep kernel: all weight-dependent transcendentals ----------------
// ws layout (float2): [0..69] gate table; [70..1093] rz1 per-amp (cos,sin);
//                     [1094..2117] rz2 per-amp (cos,sin)
__global__ void qae_prep(const float* __restrict__ w, float2* __restrict__ ws) {
  const int i = threadIdx.x;          // 0..1023
  if (i < 50) {                       // half-angle gate coefficients
    float s, c; __sincosf(0.5f * w[i], &s, &c);
    ws[i] = make_float2(c, s);
  } else if (i < 56) {                // FULL angle: Heisenberg output transform w[50..55]
    float s, c; __sincosf(w[i], &s, &c);
    ws[i] = make_float2(c, s);
  } else if (i < 60) {
    ws[i] = make_float2(1.f, 0.f);    // unused
  } else if (i < 70) {                // folded RY_b(layer1)+RY_c(layer2)
    const int q = i - 60;
    float s, c; __sincosf(0.5f * (w[20 + q] + w[30 + q]), &s, &c);
    ws[i] = make_float2(c, s);
  }
  // per-amplitude RZ phases: phi(i) = sum_b (bit b of i ? +.5 : -.5) * w[off + 9 - b]
  float p1 = 0.f, p2 = 0.f;
#pragma unroll
  for (int b = 0; b < 10; ++b) {
    const float sg = ((i >> b) & 1) ? 0.5f : -0.5f;
    p1 += sg * w[10 + 9 - b];
    p2 += sg * w[40 + 9 - b];
  }
  float s, c;
  __sincosf(p1, &s, &c); ws[70 + i]        = make_float2(c, s);
  __sincosf(p2, &s, &c); ws[70 + 1024 + i] = make_float2(c, s);
}

// ---------------- main kernel: 2 waves/block, 2 rows/wave, zero barriers ----------------
__global__ __launch_bounds__(128, 4) void qae_main(const float* __restrict__ x,
                                                   const float2* __restrict__ gt,
                                                   float* __restrict__ out, int Btot) {
  __shared__ f2 lds[2 * 1024];          // 8KB wave-private regions
  const int tid  = threadIdx.x;
  const int lane = tid & 63;
  const int wid  = tid >> 6;
  const int gw   = blockIdx.x * 2 + wid;
  const int b0   = gw * 2, b1 = b0 + 1;
  if (b0 >= Btot) return;
  const bool has1 = (b1 < Btot);
  f2* stc = lds + (wid << 10);
  const float2* rz1 = gt + 70;
  const float2* rz2 = gt + 70 + 1024;

  // Load 2 rows, layout A: g[r] = (row0[i], row1[i]), i = (lane<<4)|r; i>=768 zero.
  f2 g[16];
  f2 ss = (f2){0.f, 0.f};
  const float* x0 = x + (size_t)b0 * DIN;
  const float* x1 = x + (size_t)b1 * DIN;
#pragma unroll
  for (int t = 0; t < 4; ++t) {
    const int idx = lane * 16 + 4 * t;
    float4 va = make_float4(0.f, 0.f, 0.f, 0.f);
    float4 vb = make_float4(0.f, 0.f, 0.f, 0.f);
    if (idx < DIN) {
      va = *reinterpret_cast<const float4*>(x0 + idx);
      if (has1) vb = *reinterpret_cast<const float4*>(x1 + idx);
    }
    g[4*t+0] = (f2){va.x, vb.x}; g[4*t+1] = (f2){va.y, vb.y};
    g[4*t+2] = (f2){va.z, vb.z}; g[4*t+3] = (f2){va.w, vb.w};
#pragma unroll
    for (int k = 0; k < 4; ++k) ss += g[4*t+k] * g[4*t+k];
  }
  ss = wsum2(ss);
  const f2 inv = (f2){1.f / fmaxf(ss.x, 1e-16f), 1.f / fmaxf(ss.y, 1e-16f)};

  float2 cs;
  // ===== layer 1 RY round (w[0..9]) — REAL state, layout A: r bits 3..0 <-> q6..q9 =====
  cs = gt[6]; ry1<3>(g, cs.x, cs.y);
  cs = gt[7]; ry1<2>(g, cs.x, cs.y);
  cs = gt[8]; ry1<1>(g, cs.x, cs.y);
  cs = gt[9]; ry1<0>(g, cs.x, cs.y);
  cs = gt[4]; ry1_shfl<2>(lane, g, cs.x, cs.y);   // q4 <-> lane bit 1
  cs = gt[5]; ry1_shfl<1>(lane, g, cs.x, cs.y);   // q5 <-> lane bit 0

  // T1: A->B (real, rows travel inside the f2 cell)
#pragma unroll
  for (int r = 0; r < 16; ++r) stc[swz((lane << 4) | r)] = g[r];
#pragma unroll
  for (int r = 0; r < 16; ++r) g[r] = stc[swz((r << 6) | lane)];

  // B: r bits 3..0 <-> q0..q3
  cs = gt[0]; ry1<3>(g, cs.x, cs.y);
  cs = gt[1]; ry1<2>(g, cs.x, cs.y);
  cs = gt[2]; ry1<1>(g, cs.x, cs.y);
  cs = gt[3]; ry1<0>(g, cs.x, cs.y);

  // RZ1 (table): real -> complex, rows packed: re/im separate register files
  f2 re[16], im[16];
#pragma unroll
  for (int r = 0; r < 16; ++r) {
    const float2 t = rz1[(r << 6) | lane];
    re[r] = g[r] * t.x;
    im[r] = g[r] * t.y;
  }

  // T2: CNOT ring 1 fused into B->A transpose (two b64 passes through 8KB)
#pragma unroll
  for (int r = 0; r < 16; ++r) stc[swz((r << 6) | lane)] = re[r];
#pragma unroll
  for (int r = 0; r < 16; ++r) re[r] = stc[swz(cnotL((lane << 4) | r))];
#pragma unroll
  for (int r = 0; r < 16; ++r) stc[swz((r << 6) | lane)] = im[r];
#pragma unroll
  for (int r = 0; r < 16; ++r) im[r] = stc[swz(cnotL((lane << 4) | r))];

  // ===== combined RY round (folded, gt[60..69]), layout A =====
  cs = gt[66]; ry2<3>(re, im, cs.x, cs.y);
  cs = gt[67]; ry2<2>(re, im, cs.x, cs.y);
  cs = gt[68]; ry2<1>(re, im, cs.x, cs.y);
  cs = gt[69]; ry2<0>(re, im, cs.x, cs.y);
  cs = gt[64]; ry1_shfl<2>(lane, re, cs.x, cs.y); ry1_shfl<2>(lane, im, cs.x, cs.y);
  cs = gt[65]; ry1_shfl<1>(lane, re, cs.x, cs.y); ry1_shfl<1>(lane, im, cs.x, cs.y);

  // T3: A->B
#pragma unroll
  for (int r = 0; r < 16; ++r) stc[swz((lane << 4) | r)] = re[r];
#pragma unroll
  for (int r = 0; r < 16; ++r) re[r] = stc[swz((r << 6) | lane)];
#pragma unroll
  for (int r = 0; r < 16; ++r) stc[swz((lane << 4) | r)] = im[r];
#pragma unroll
  for (int r = 0; r < 16; ++r) im[r] = stc[swz((r << 6) | lane)];

  cs = gt[60]; ry2<3>(re, im, cs.x, cs.y);
  cs = gt[61]; ry2<2>(re, im, cs.x, cs.y);
  cs = gt[62]; ry2<1>(re, im, cs.x, cs.y);
  cs = gt[63]; ry2<0>(re, im, cs.x, cs.y);

  // RZ2 (table)
#pragma unroll
  for (int r = 0; r < 16; ++r) {
    const float2 t = rz2[(r << 6) | lane];
    const f2 nre = re[r] * t.x - im[r] * t.y;
    im[r] = re[r] * t.y + im[r] * t.x;
    re[r] = nre;
  }

  // T4: CNOT ring 2, gather read directly into layout B (final RY folded at output)
#pragma unroll
  for (int r = 0; r < 16; ++r) stc[swz((r << 6) | lane)] = re[r];
#pragma unroll
  for (int r = 0; r < 16; ++r) re[r] = stc[swz(cnotL((r << 6) | lane))];
#pragma unroll
  for (int r = 0; r < 16; ++r) stc[swz((r << 6) | lane)] = im[r];
#pragma unroll
  for (int r = 0; r < 16; ++r) im[r] = stc[swz(cnotL((r << 6) | lane))];

  // ===== expectation values (layout B), rows packed in f2 =====
  f2 aX[6], aY[6], aZ[6];
#pragma unroll
  for (int q = 0; q < 6; ++q) { aX[q] = (f2){0.f,0.f}; aY[q] = (f2){0.f,0.f}; aZ[q] = (f2){0.f,0.f}; }

  {
    f2 psum = (f2){0.f, 0.f};
#pragma unroll
    for (int r = 0; r < 16; ++r) {
      const f2 p = re[r] * re[r] + im[r] * im[r];
      psum += p;
      aZ[0] += (r & 8) ? -p : p;
      aZ[1] += (r & 4) ? -p : p;
      aZ[2] += (r & 2) ? -p : p;
      aZ[3] += (r & 1) ? -p : p;
    }
    aZ[4] = ((lane >> 5) & 1) ? -psum : psum;
    aZ[5] = ((lane >> 4) & 1) ? -psum : psum;
  }

  xyr<3>(re, im, aX[0], aY[0]);
  xyr<2>(re, im, aX[1], aY[1]);
  xyr<1>(re, im, aX[2], aY[2]);
  xyr<0>(re, im, aX[3], aY[3]);
  xys<32>(lane, re, im, aX[4], aY[4]);
  xys<16>(lane, re, im, aX[5], aY[5]);

#pragma unroll
  for (int q = 0; q < 6; ++q) {
    aX[q] = wsum2(aX[q]);
    aY[q] = wsum2(aY[q]);
    aZ[q] = wsum2(aZ[q]);
  }

  // Heisenberg transform of the dropped final RY round (full angles gt[50+q]),
  // computed redundantly in all lanes (pk, both rows), stored by lanes 0/1.
  f2 o[18];
#pragma unroll
  for (int q = 0; q < 6; ++q) {
    const float2 fa = gt[50 + q];
    const float fac = (q < 4) ? 2.f : 1.f;     // xyr pairs counted once; xys twice
    const f2 X = aX[q] * fac, Y = aY[q] * fac, Z = aZ[q];
    o[q]      = (X * fa.x + Z * fa.y) * inv;
    o[6 + q]  = Y * inv;
    o[12 + q] = (Z * fa.x - X * fa.y) * inv;
  }
  if (lane == 0) {
    float* ob = out + (size_t)b0 * 18;
#pragma unroll
    for (int k = 0; k < 18; ++k) ob[k] = o[k].x;
  } else if (lane == 1 && has1) {
    float* ob = out + (size_t)b1 * 18;
#pragma unroll
    for (int k = 0; k < 18; ++k) ob[k] = o[k].y;
  }
}

extern "C" void kernel_launch(void* const* d_in, const int* in_sizes, int n_in,
                              void* d_out, int out_size, void* d_ws, size_t ws_size,
                              hipStream_t stream) {
  const float* x = (const float*)d_in[0];
  const float* w = (const float*)d_in[1];
  float* out = (float*)d_out;
  float2* ws = (float2*)d_ws;
  const int B = in_sizes[0] / DIN;
  qae_prep<<<dim3(1), dim3(1024), 0, stream>>>(w, ws);
  const int grid = (B + 3) / 4;     // 2 waves/block x 2 rows/wave
  qae_main<<<dim3(grid), dim3(128), 0, stream>>>(x, (const float2*)ws, out, B);
}

// Round 8
// 114.924 us; speedup vs baseline: 1.7864x; 1.0852x over previous
//
#include <hip/hip_runtime.h>

#define DIN 768

typedef float f2 __attribute__((ext_vector_type(2)));
typedef int i2v __attribute__((ext_vector_type(2)));

#if __has_builtin(__builtin_amdgcn_permlane32_swap)
#define HAVE_PL32 1
#endif
#if __has_builtin(__builtin_amdgcn_permlane16_swap)
#define HAVE_PL16 1
#endif

__device__ __forceinline__ int f2i(float v) { return __builtin_bit_cast(int, v); }
__device__ __forceinline__ float i2f(int v) { return __builtin_bit_cast(float, v); }

// DPP ctrl: quad_perm xor1 = 0xB1 ; xor2 = 0x4E ; row_ror:4 = 0x124 ; row_ror:8 = 0x128
template<int CTRL>
__device__ __forceinline__ float dppf(float v) {
  const int i = f2i(v);
  return i2f(__builtin_amdgcn_update_dpp(i, i, CTRL, 0xF, 0xF, true));
}
template<int CTRL>
__device__ __forceinline__ f2 dppf2(f2 v) {
  f2 r; r.x = dppf<CTRL>(v.x); r.y = dppf<CTRL>(v.y); return r;
}

// Full 64-lane sum of both f2 components (2 rows at once). Zero DS ops.
__device__ __forceinline__ f2 wsum2(f2 v) {
  v += dppf2<0xB1>(v);
  v += dppf2<0x4E>(v);
  v += dppf2<0x124>(v);
  v += dppf2<0x128>(v);
#ifdef HAVE_PL16
  { i2v rx = __builtin_amdgcn_permlane16_swap(f2i(v.x), f2i(v.x), false, false);
    i2v ry = __builtin_amdgcn_permlane16_swap(f2i(v.y), f2i(v.y), false, false);
    v.x = i2f(rx.x) + i2f(rx.y);
    v.y = i2f(ry.x) + i2f(ry.y); }
#else
  v.x += __shfl_xor(v.x, 16); v.y += __shfl_xor(v.y, 16);
#endif
#ifdef HAVE_PL32
  { i2v rx = __builtin_amdgcn_permlane32_swap(f2i(v.x), f2i(v.x), false, false);
    i2v ry = __builtin_amdgcn_permlane32_swap(f2i(v.y), f2i(v.y), false, false);
    v.x = i2f(rx.x) + i2f(rx.y);
    v.y = i2f(ry.x) + i2f(ry.y); }
#else
  v.x += __shfl_xor(v.x, 32); v.y += __shfl_xor(v.y, 32);
#endif
  return v;
}

// xor-shuffle of an f2, VALU-only for masks 1,2,16,32.
template<int MASK>
__device__ __forceinline__ f2 shflx_f2(f2 v, int lane) {
  f2 r;
  if constexpr (MASK == 1) {
    r = dppf2<0xB1>(v);
  } else if constexpr (MASK == 2) {
    r = dppf2<0x4E>(v);
  } else if constexpr (MASK == 16) {
#ifdef HAVE_PL16
    const i2v a = __builtin_amdgcn_permlane16_swap(f2i(v.x), f2i(v.x), false, false);
    const i2v b = __builtin_amdgcn_permlane16_swap(f2i(v.y), f2i(v.y), false, false);
    const bool hi = (lane >> 4) & 1;
    r.x = hi ? i2f(a.x) : i2f(a.y);
    r.y = hi ? i2f(b.x) : i2f(b.y);
#else
    r.x = __shfl_xor(v.x, 16); r.y = __shfl_xor(v.y, 16);
#endif
  } else if constexpr (MASK == 32) {
#ifdef HAVE_PL32
    const i2v a = __builtin_amdgcn_permlane32_swap(f2i(v.x), f2i(v.x), false, false);
    const i2v b = __builtin_amdgcn_permlane32_swap(f2i(v.y), f2i(v.y), false, false);
    const bool lo = lane < 32;
    r.x = lo ? i2f(a.y) : i2f(a.x);
    r.y = lo ? i2f(b.y) : i2f(b.x);
#else
    r.x = __shfl_xor(v.x, 32); r.y = __shfl_xor(v.y, 32);
#endif
  } else {
    r.x = __shfl_xor(v.x, MASK); r.y = __shfl_xor(v.y, MASK);
  }
  return r;
}

__device__ __forceinline__ int swz(int i) { return i ^ ((i >> 4) & 31); }

// Composite gather map of the CNOT ring CNOT(0,1)..CNOT(9,0): Final[i] = In[cnotL(i)]
__device__ __forceinline__ int cnotL(int i) {
  const int b9 = (i >> 9) & 1;
  const int b8 = (i >> 8) & 1;
  const int b0 = i & 1;
  return ((i ^ (i >> 1)) & 0xFF) | ((b8 ^ b9 ^ b0) << 8) | ((b9 ^ b0) << 9);
}

// RY on a 16-reg component array (rows packed in f2). Real 2x2 acts per component.
template<int RB>
__device__ __forceinline__ void ry1(f2 (&a)[16], float c, float s) {
#pragma unroll
  for (int r = 0; r < 16; ++r) {
    if (!(r & (1 << RB))) {
      const int p = r | (1 << RB);
      const f2 a0 = a[r], a1 = a[p];
      a[r] = a0 * c - a1 * s;
      a[p] = a1 * c + a0 * s;
    }
  }
}
template<int RB>
__device__ __forceinline__ void ry2(f2 (&re)[16], f2 (&im)[16], float c, float s) {
  ry1<RB>(re, c, s);
  ry1<RB>(im, c, s);
}
template<int MASK>
__device__ __forceinline__ void ry1_shfl(int lane, f2 (&a)[16], float c, float s) {
  const float ss = (lane & MASK) ? s : -s;
#pragma unroll
  for (int r = 0; r < 16; ++r) {
    const f2 p = shflx_f2<MASK>(a[r], lane);
    a[r] = a[r] * c + p * ss;
  }
}

// X/Y accumulate, register-pair qubit (each unordered pair once -> fac 2 at output)
template<int RB>
__device__ __forceinline__ void xyr(const f2 (&re)[16], const f2 (&im)[16], f2& aX, f2& aY) {
#pragma unroll
  for (int r = 0; r < 16; ++r) {
    if (!(r & (1 << RB))) {
      const int p = r | (1 << RB);
      aX += re[r] * re[p] + im[r] * im[p];
      aY += re[r] * im[p] - im[r] * re[p];
    }
  }
}
// X/Y accumulate, lane-bit qubit (each ordered pair counted -> net 2x already)
template<int MASK>
__device__ __forceinline__ void xys(int lane, const f2 (&re)[16], const f2 (&im)[16], f2& aX, f2& aY) {
  const float sgn = (lane & MASK) ? -1.f : 1.f;
#pragma unroll
  for (int r = 0; r < 16; ++r) {
    const f2 pr = shflx_f2<MASK>(re[r], lane);
    const f2 pi = shflx_f2<MASK>(im[r], lane);
    aX += re[r] * pr + im[r] * pi;
    aY += (re[r] * pi - im[r] * pr) * sgn;
  }
}

// ---------------- prep kernel: all weight-dependent transcendentals ----------------
// ws layout (float2): [0..69] gate table; [70..1093] rz1 per-amp (cos,sin);
//                     [1094..2117] rz2 per-amp (cos,sin)
__global__ void qae_prep(const float* __restrict__ w, float2* __restrict__ ws) {
  const int i = threadIdx.x;          // 0..1023
  if (i < 50) {                       // half-angle gate coefficients
    float s, c; __sincosf(0.5f * w[i], &s, &c);
    ws[i] = make_float2(c, s);
  } else if (i < 56) {                // FULL angle: Heisenberg output transform w[50..55]
    float s, c; __sincosf(w[i], &s, &c);
    ws[i] = make_float2(c, s);
  } else if (i < 60) {
    ws[i] = make_float2(1.f, 0.f);    // unused
  } else if (i < 70) {                // folded RY_b(layer1)+RY_c(layer2)
    const int q = i - 60;
    float s, c; __sincosf(0.5f * (w[20 + q] + w[30 + q]), &s, &c);
    ws[i] = make_float2(c, s);
  }
  // per-amplitude RZ phases: phi(i) = sum_b (bit b of i ? +.5 : -.5) * w[off + 9 - b]
  float p1 = 0.f, p2 = 0.f;
#pragma unroll
  for (int b = 0; b < 10; ++b) {
    const float sg = ((i >> b) & 1) ? 0.5f : -0.5f;
    p1 += sg * w[10 + 9 - b];
    p2 += sg * w[40 + 9 - b];
  }
  float s, c;
  __sincosf(p1, &s, &c); ws[70 + i]        = make_float2(c, s);
  __sincosf(p2, &s, &c); ws[70 + 1024 + i] = make_float2(c, s);
}

// ---------------- main kernel: 2 waves/block, 2 rows/wave, zero barriers ----------------
__global__ __launch_bounds__(128) void qae_main(const float* __restrict__ x,
                                                const float2* __restrict__ gt,
                                                float* __restrict__ out, int Btot) {
  __shared__ f2 lds[2 * 1024];          // 8KB wave-private regions
  const int tid  = threadIdx.x;
  const int lane = tid & 63;
  const int wid  = tid >> 6;
  const int gw   = blockIdx.x * 2 + wid;
  const int b0   = gw * 2, b1 = b0 + 1;
  if (b0 >= Btot) return;
  const bool has1 = (b1 < Btot);
  f2* stc = lds + (wid << 10);
  const float2* rz1 = gt + 70;
  const float2* rz2 = gt + 70 + 1024;

  // Load 2 rows, layout A: g[r] = (row0[i], row1[i]), i = (lane<<4)|r; i>=768 zero.
  f2 g[16];
  f2 ss = (f2){0.f, 0.f};
  const float* x0 = x + (size_t)b0 * DIN;
  const float* x1 = x + (size_t)b1 * DIN;
#pragma unroll
  for (int t = 0; t < 4; ++t) {
    const int idx = lane * 16 + 4 * t;
    float4 va = make_float4(0.f, 0.f, 0.f, 0.f);
    float4 vb = make_float4(0.f, 0.f, 0.f, 0.f);
    if (idx < DIN) {
      va = *reinterpret_cast<const float4*>(x0 + idx);
      if (has1) vb = *reinterpret_cast<const float4*>(x1 + idx);
    }
    g[4*t+0] = (f2){va.x, vb.x}; g[4*t+1] = (f2){va.y, vb.y};
    g[4*t+2] = (f2){va.z, vb.z}; g[4*t+3] = (f2){va.w, vb.w};
#pragma unroll
    for (int k = 0; k < 4; ++k) ss += g[4*t+k] * g[4*t+k];
  }
  ss = wsum2(ss);
  const f2 inv = (f2){1.f / fmaxf(ss.x, 1e-16f), 1.f / fmaxf(ss.y, 1e-16f)};

  float2 cs;
  // ===== layer 1 RY round (w[0..9]) — REAL state, layout A: r bits 3..0 <-> q6..q9 =====
  cs = gt[6]; ry1<3>(g, cs.x, cs.y);
  cs = gt[7]; ry1<2>(g, cs.x, cs.y);
  cs = gt[8]; ry1<1>(g, cs.x, cs.y);
  cs = gt[9]; ry1<0>(g, cs.x, cs.y);
  cs = gt[4]; ry1_shfl<2>(lane, g, cs.x, cs.y);   // q4 <-> lane bit 1
  cs = gt[5]; ry1_shfl<1>(lane, g, cs.x, cs.y);   // q5 <-> lane bit 0

  // T1: A->B (real, rows travel inside the f2 cell)
#pragma unroll
  for (int r = 0; r < 16; ++r) stc[swz((lane << 4) | r)] = g[r];
#pragma unroll
  for (int r = 0; r < 16; ++r) g[r] = stc[swz((r << 6) | lane)];

  // B: r bits 3..0 <-> q0..q3
  cs = gt[0]; ry1<3>(g, cs.x, cs.y);
  cs = gt[1]; ry1<2>(g, cs.x, cs.y);
  cs = gt[2]; ry1<1>(g, cs.x, cs.y);
  cs = gt[3]; ry1<0>(g, cs.x, cs.y);

  // RZ1 (table): real -> complex, rows packed: re/im separate register files
  f2 re[16], im[16];
#pragma unroll
  for (int r = 0; r < 16; ++r) {
    const float2 t = rz1[(r << 6) | lane];
    re[r] = g[r] * t.x;
    im[r] = g[r] * t.y;
  }

  // T2: CNOT ring 1 fused into B->A transpose (two b64 passes through 8KB)
#pragma unroll
  for (int r = 0; r < 16; ++r) stc[swz((r << 6) | lane)] = re[r];
#pragma unroll
  for (int r = 0; r < 16; ++r) re[r] = stc[swz(cnotL((lane << 4) | r))];
#pragma unroll
  for (int r = 0; r < 16; ++r) stc[swz((r << 6) | lane)] = im[r];
#pragma unroll
  for (int r = 0; r < 16; ++r) im[r] = stc[swz(cnotL((lane << 4) | r))];

  // ===== combined RY round (folded, gt[60..69]), layout A =====
  cs = gt[66]; ry2<3>(re, im, cs.x, cs.y);
  cs = gt[67]; ry2<2>(re, im, cs.x, cs.y);
  cs = gt[68]; ry2<1>(re, im, cs.x, cs.y);
  cs = gt[69]; ry2<0>(re, im, cs.x, cs.y);
  cs = gt[64]; ry1_shfl<2>(lane, re, cs.x, cs.y); ry1_shfl<2>(lane, im, cs.x, cs.y);
  cs = gt[65]; ry1_shfl<1>(lane, re, cs.x, cs.y); ry1_shfl<1>(lane, im, cs.x, cs.y);

  // T3: A->B
#pragma unroll
  for (int r = 0; r < 16; ++r) stc[swz((lane << 4) | r)] = re[r];
#pragma unroll
  for (int r = 0; r < 16; ++r) re[r] = stc[swz((r << 6) | lane)];
#pragma unroll
  for (int r = 0; r < 16; ++r) stc[swz((lane << 4) | r)] = im[r];
#pragma unroll
  for (int r = 0; r < 16; ++r) im[r] = stc[swz((r << 6) | lane)];

  cs = gt[60]; ry2<3>(re, im, cs.x, cs.y);
  cs = gt[61]; ry2<2>(re, im, cs.x, cs.y);
  cs = gt[62]; ry2<1>(re, im, cs.x, cs.y);
  cs = gt[63]; ry2<0>(re, im, cs.x, cs.y);

  // RZ2 (table)
#pragma unroll
  for (int r = 0; r < 16; ++r) {
    const float2 t = rz2[(r << 6) | lane];
    const f2 nre = re[r] * t.x - im[r] * t.y;
    im[r] = re[r] * t.y + im[r] * t.x;
    re[r] = nre;
  }

  // T4: CNOT ring 2, gather read directly into layout B (final RY folded at output)
#pragma unroll
  for (int r = 0; r < 16; ++r) stc[swz((r << 6) | lane)] = re[r];
#pragma unroll
  for (int r = 0; r < 16; ++r) re[r] = stc[swz(cnotL((r << 6) | lane))];
#pragma unroll
  for (int r = 0; r < 16; ++r) stc[swz((r << 6) | lane)] = im[r];
#pragma unroll
  for (int r = 0; r < 16; ++r) im[r] = stc[swz(cnotL((r << 6) | lane))];

  // ===== expectation values (layout B), rows packed in f2 =====
  f2 aX[6], aY[6], aZ[6];
#pragma unroll
  for (int q = 0; q < 6; ++q) { aX[q] = (f2){0.f,0.f}; aY[q] = (f2){0.f,0.f}; aZ[q] = (f2){0.f,0.f}; }

  {
    f2 psum = (f2){0.f, 0.f};
#pragma unroll
    for (int r = 0; r < 16; ++r) {
      const f2 p = re[r] * re[r] + im[r] * im[r];
      psum += p;
      aZ[0] += (r & 8) ? -p : p;
      aZ[1] += (r & 4) ? -p : p;
      aZ[2] += (r & 2) ? -p : p;
      aZ[3] += (r & 1) ? -p : p;
    }
    aZ[4] = ((lane >> 5) & 1) ? -psum : psum;
    aZ[5] = ((lane >> 4) & 1) ? -psum : psum;
  }

  xyr<3>(re, im, aX[0], aY[0]);
  xyr<2>(re, im, aX[1], aY[1]);
  xyr<1>(re, im, aX[2], aY[2]);
  xyr<0>(re, im, aX[3], aY[3]);
  xys<32>(lane, re, im, aX[4], aY[4]);
  xys<16>(lane, re, im, aX[5], aY[5]);

#pragma unroll
  for (int q = 0; q < 6; ++q) {
    aX[q] = wsum2(aX[q]);
    aY[q] = wsum2(aY[q]);
    aZ[q] = wsum2(aZ[q]);
  }

  // Heisenberg transform of the dropped final RY round (full angles gt[50+q]).
  f2 o[18];
#pragma unroll
  for (int q = 0; q < 6; ++q) {
    const float2 fa = gt[50 + q];
    const float fac = (q < 4) ? 2.f : 1.f;     // xyr pairs counted once; xys twice
    const f2 X = aX[q] * fac, Y = aY[q] * fac, Z = aZ[q];
    o[q]      = (X * fa.x + Z * fa.y) * inv;
    o[6 + q]  = Y * inv;
    o[12 + q] = (Z * fa.x - X * fa.y) * inv;
  }

  // Dense store: rows b0,b1 are contiguous (36 floats, 16B-aligned since b0 even).
  if (lane == 0) {
    float* ob = out + (size_t)b0 * 18;
    if (has1) {
      float4* ob4 = reinterpret_cast<float4*>(ob);
      ob4[0] = make_float4(o[0].x,  o[1].x,  o[2].x,  o[3].x);
      ob4[1] = make_float4(o[4].x,  o[5].x,  o[6].x,  o[7].x);
      ob4[2] = make_float4(o[8].x,  o[9].x,  o[10].x, o[11].x);
      ob4[3] = make_float4(o[12].x, o[13].x, o[14].x, o[15].x);
      ob4[4] = make_float4(o[16].x, o[17].x, o[0].y,  o[1].y);
      ob4[5] = make_float4(o[2].y,  o[3].y,  o[4].y,  o[5].y);
      ob4[6] = make_float4(o[6].y,  o[7].y,  o[8].y,  o[9].y);
      ob4[7] = make_float4(o[10].y, o[11].y, o[12].y, o[13].y);
      ob4[8] = make_float4(o[14].y, o[15].y, o[16].y, o[17].y);
    } else {
#pragma unroll
      for (int k = 0; k < 18; ++k) ob[k] = o[k].x;
    }
  }
}

extern "C" void kernel_launch(void* const* d_in, const int* in_sizes, int n_in,
                              void* d_out, int out_size, void* d_ws, size_t ws_size,
                              hipStream_t stream) {
  const float* x = (const float*)d_in[0];
  const float* w = (const float*)d_in[1];
  float* out = (float*)d_out;
  float2* ws = (float2*)d_ws;
  const int B = in_sizes[0] / DIN;
  qae_prep<<<dim3(1), dim3(1024), 0, stream>>>(w, ws);
  const int grid = (B + 3) / 4;     // 2 waves/block x 2 rows/wave
  qae_main<<<dim3(grid), dim3(128), 0, stream>>>(x, (const float2*)ws, out, B);
}

// Round 9
// 106.353 us; speedup vs baseline: 1.9304x; 1.0806x over previous
//
#include <hip/hip_runtime.h>

#define DIN 768

typedef float f2 __attribute__((ext_vector_type(2)));
typedef int i2v __attribute__((ext_vector_type(2)));

#if __has_builtin(__builtin_amdgcn_permlane32_swap)
#define HAVE_PL32 1
#endif
#if __has_builtin(__builtin_amdgcn_permlane16_swap)
#define HAVE_PL16 1
#endif

__device__ __forceinline__ int f2i(float v) { return __builtin_bit_cast(int, v); }
__device__ __forceinline__ float i2f(int v) { return __builtin_bit_cast(float, v); }

// DPP ctrl: quad_perm xor1 = 0xB1 ; xor2 = 0x4E ; row_ror:4 = 0x124 ; row_ror:8 = 0x128
template<int CTRL>
__device__ __forceinline__ float dppf(float v) {
  const int i = f2i(v);
  return i2f(__builtin_amdgcn_update_dpp(i, i, CTRL, 0xF, 0xF, true));
}
template<int CTRL>
__device__ __forceinline__ f2 dppf2(f2 v) {
  f2 r; r.x = dppf<CTRL>(v.x); r.y = dppf<CTRL>(v.y); return r;
}

// Full 64-lane sum of both f2 components. Zero DS ops. (Used once, for sumsq.)
__device__ __forceinline__ f2 wsum2(f2 v) {
  v += dppf2<0xB1>(v);
  v += dppf2<0x4E>(v);
  v += dppf2<0x124>(v);
  v += dppf2<0x128>(v);
#ifdef HAVE_PL16
  { i2v rx = __builtin_amdgcn_permlane16_swap(f2i(v.x), f2i(v.x), false, false);
    i2v ry = __builtin_amdgcn_permlane16_swap(f2i(v.y), f2i(v.y), false, false);
    v.x = i2f(rx.x) + i2f(rx.y);
    v.y = i2f(ry.x) + i2f(ry.y); }
#else
  v.x += __shfl_xor(v.x, 16); v.y += __shfl_xor(v.y, 16);
#endif
#ifdef HAVE_PL32
  { i2v rx = __builtin_amdgcn_permlane32_swap(f2i(v.x), f2i(v.x), false, false);
    i2v ry = __builtin_amdgcn_permlane32_swap(f2i(v.y), f2i(v.y), false, false);
    v.x = i2f(rx.x) + i2f(rx.y);
    v.y = i2f(ry.x) + i2f(ry.y); }
#else
  v.x += __shfl_xor(v.x, 32); v.y += __shfl_xor(v.y, 32);
#endif
  return v;
}

// xor-shuffle of an f2, VALU-only for masks 1,2,16,32.
template<int MASK>
__device__ __forceinline__ f2 shflx_f2(f2 v, int lane) {
  f2 r;
  if constexpr (MASK == 1) {
    r = dppf2<0xB1>(v);
  } else if constexpr (MASK == 2) {
    r = dppf2<0x4E>(v);
  } else if constexpr (MASK == 16) {
#ifdef HAVE_PL16
    const i2v a = __builtin_amdgcn_permlane16_swap(f2i(v.x), f2i(v.x), false, false);
    const i2v b = __builtin_amdgcn_permlane16_swap(f2i(v.y), f2i(v.y), false, false);
    const bool hi = (lane >> 4) & 1;
    r.x = hi ? i2f(a.x) : i2f(a.y);
    r.y = hi ? i2f(b.x) : i2f(b.y);
#else
    r.x = __shfl_xor(v.x, 16); r.y = __shfl_xor(v.y, 16);
#endif
  } else if constexpr (MASK == 32) {
#ifdef HAVE_PL32
    const i2v a = __builtin_amdgcn_permlane32_swap(f2i(v.x), f2i(v.x), false, false);
    const i2v b = __builtin_amdgcn_permlane32_swap(f2i(v.y), f2i(v.y), false, false);
    const bool lo = lane < 32;
    r.x = lo ? i2f(a.y) : i2f(a.x);
    r.y = lo ? i2f(b.y) : i2f(b.x);
#else
    r.x = __shfl_xor(v.x, 32); r.y = __shfl_xor(v.y, 32);
#endif
  } else {
    r.x = __shfl_xor(v.x, MASK); r.y = __shfl_xor(v.y, MASK);
  }
  return r;
}

__device__ __forceinline__ int swz(int i) { return i ^ ((i >> 4) & 31); }

// Composite gather map of the CNOT ring CNOT(0,1)..CNOT(9,0): Final[i] = In[cnotL(i)]
__device__ __forceinline__ int cnotL(int i) {
  const int b9 = (i >> 9) & 1;
  const int b8 = (i >> 8) & 1;
  const int b0 = i & 1;
  return ((i ^ (i >> 1)) & 0xFF) | ((b8 ^ b9 ^ b0) << 8) | ((b9 ^ b0) << 9);
}

// RY on a 16-reg component array (rows packed in f2). Real 2x2 acts per component.
template<int RB>
__device__ __forceinline__ void ry1(f2 (&a)[16], float c, float s) {
#pragma unroll
  for (int r = 0; r < 16; ++r) {
    if (!(r & (1 << RB))) {
      const int p = r | (1 << RB);
      const f2 a0 = a[r], a1 = a[p];
      a[r] = a0 * c - a1 * s;
      a[p] = a1 * c + a0 * s;
    }
  }
}
template<int RB>
__device__ __forceinline__ void ry2(f2 (&re)[16], f2 (&im)[16], float c, float s) {
  ry1<RB>(re, c, s);
  ry1<RB>(im, c, s);
}
template<int MASK>
__device__ __forceinline__ void ry1_shfl(int lane, f2 (&a)[16], float c, float s) {
  const float ss = (lane & MASK) ? s : -s;
#pragma unroll
  for (int r = 0; r < 16; ++r) {
    const f2 p = shflx_f2<MASK>(a[r], lane);
    a[r] = a[r] * c + p * ss;
  }
}

// X/Y accumulate, register-pair qubit (each unordered pair once -> fac 2 at output)
template<int RB>
__device__ __forceinline__ void xyr(const f2 (&re)[16], const f2 (&im)[16], f2& aX, f2& aY) {
#pragma unroll
  for (int r = 0; r < 16; ++r) {
    if (!(r & (1 << RB))) {
      const int p = r | (1 << RB);
      aX += re[r] * re[p] + im[r] * im[p];
      aY += re[r] * im[p] - im[r] * re[p];
    }
  }
}
// X/Y accumulate, lane-bit qubit (each ordered pair counted -> net 2x already)
template<int MASK>
__device__ __forceinline__ void xys(int lane, const f2 (&re)[16], const f2 (&im)[16], f2& aX, f2& aY) {
  const float sgn = (lane & MASK) ? -1.f : 1.f;
#pragma unroll
  for (int r = 0; r < 16; ++r) {
    const f2 pr = shflx_f2<MASK>(re[r], lane);
    const f2 pi = shflx_f2<MASK>(im[r], lane);
    aX += re[r] * pr + im[r] * pi;
    aY += (re[r] * pi - im[r] * pr) * sgn;
  }
}

// ---------------- prep kernel: all weight-dependent transcendentals ----------------
// ws layout (float2): [0..69] gate table; [70..1093] rz1 per-amp (cos,sin);
//                     [1094..2117] rz2 per-amp (cos,sin)
__global__ void qae_prep(const float* __restrict__ w, float2* __restrict__ ws) {
  const int i = threadIdx.x;          // 0..1023
  if (i < 50) {                       // half-angle gate coefficients
    float s, c; __sincosf(0.5f * w[i], &s, &c);
    ws[i] = make_float2(c, s);
  } else if (i < 56) {                // FULL angle: Heisenberg output transform w[50..55]
    float s, c; __sincosf(w[i], &s, &c);
    ws[i] = make_float2(c, s);
  } else if (i < 60) {
    ws[i] = make_float2(1.f, 0.f);    // unused
  } else if (i < 70) {                // folded RY_b(layer1)+RY_c(layer2)
    const int q = i - 60;
    float s, c; __sincosf(0.5f * (w[20 + q] + w[30 + q]), &s, &c);
    ws[i] = make_float2(c, s);
  }
  // per-amplitude RZ phases: phi(i) = sum_b (bit b of i ? +.5 : -.5) * w[off + 9 - b]
  float p1 = 0.f, p2 = 0.f;
#pragma unroll
  for (int b = 0; b < 10; ++b) {
    const float sg = ((i >> b) & 1) ? 0.5f : -0.5f;
    p1 += sg * w[10 + 9 - b];
    p2 += sg * w[40 + 9 - b];
  }
  float s, c;
  __sincosf(p1, &s, &c); ws[70 + i]        = make_float2(c, s);
  __sincosf(p2, &s, &c); ws[70 + 1024 + i] = make_float2(c, s);
}

// ---------------- main kernel: 2 waves/block, 2 rows/wave, zero barriers ----------------
__global__ __launch_bounds__(128) void qae_main(const float* __restrict__ x,
                                                const float2* __restrict__ gt,
                                                float* __restrict__ out, int Btot) {
  __shared__ f2 lds[2 * 1024];          // 8KB wave-private regions
  const int tid  = threadIdx.x;
  const int lane = tid & 63;
  const int wid  = tid >> 6;
  const int gw   = blockIdx.x * 2 + wid;
  const int b0   = gw * 2, b1 = b0 + 1;
  if (b0 >= Btot) return;
  const bool has1 = (b1 < Btot);
  f2* stc = lds + (wid << 10);
  const float2* rz1 = gt + 70;
  const float2* rz2 = gt + 70 + 1024;

  // Load 2 rows, layout A: g[r] = (row0[i], row1[i]), i = (lane<<4)|r; i>=768 zero.
  f2 g[16];
  f2 ss = (f2){0.f, 0.f};
  const float* x0 = x + (size_t)b0 * DIN;
  const float* x1 = x + (size_t)b1 * DIN;
#pragma unroll
  for (int t = 0; t < 4; ++t) {
    const int idx = lane * 16 + 4 * t;
    float4 va = make_float4(0.f, 0.f, 0.f, 0.f);
    float4 vb = make_float4(0.f, 0.f, 0.f, 0.f);
    if (idx < DIN) {
      va = *reinterpret_cast<const float4*>(x0 + idx);
      if (has1) vb = *reinterpret_cast<const float4*>(x1 + idx);
    }
    g[4*t+0] = (f2){va.x, vb.x}; g[4*t+1] = (f2){va.y, vb.y};
    g[4*t+2] = (f2){va.z, vb.z}; g[4*t+3] = (f2){va.w, vb.w};
#pragma unroll
    for (int k = 0; k < 4; ++k) ss += g[4*t+k] * g[4*t+k];
  }
  ss = wsum2(ss);
  const f2 inv = (f2){1.f / fmaxf(ss.x, 1e-16f), 1.f / fmaxf(ss.y, 1e-16f)};

  float2 cs;
  // ===== layer 1 RY round (w[0..9]) — REAL state, layout A: r bits 3..0 <-> q6..q9 =====
  cs = gt[6]; ry1<3>(g, cs.x, cs.y);
  cs = gt[7]; ry1<2>(g, cs.x, cs.y);
  cs = gt[8]; ry1<1>(g, cs.x, cs.y);
  cs = gt[9]; ry1<0>(g, cs.x, cs.y);
  cs = gt[4]; ry1_shfl<2>(lane, g, cs.x, cs.y);   // q4 <-> lane bit 1
  cs = gt[5]; ry1_shfl<1>(lane, g, cs.x, cs.y);   // q5 <-> lane bit 0

  // T1: A->B (real, rows travel inside the f2 cell)
#pragma unroll
  for (int r = 0; r < 16; ++r) stc[swz((lane << 4) | r)] = g[r];
#pragma unroll
  for (int r = 0; r < 16; ++r) g[r] = stc[swz((r << 6) | lane)];

  // B: r bits 3..0 <-> q0..q3
  cs = gt[0]; ry1<3>(g, cs.x, cs.y);
  cs = gt[1]; ry1<2>(g, cs.x, cs.y);
  cs = gt[2]; ry1<1>(g, cs.x, cs.y);
  cs = gt[3]; ry1<0>(g, cs.x, cs.y);

  // RZ1 (table): real -> complex, rows packed: re/im separate register files
  f2 re[16], im[16];
#pragma unroll
  for (int r = 0; r < 16; ++r) {
    const float2 t = rz1[(r << 6) | lane];
    re[r] = g[r] * t.x;
    im[r] = g[r] * t.y;
  }

  // T2: CNOT ring 1 fused into B->A transpose (two b64 passes through 8KB)
#pragma unroll
  for (int r = 0; r < 16; ++r) stc[swz((r << 6) | lane)] = re[r];
#pragma unroll
  for (int r = 0; r < 16; ++r) re[r] = stc[swz(cnotL((lane << 4) | r))];
#pragma unroll
  for (int r = 0; r < 16; ++r) stc[swz((r << 6) | lane)] = im[r];
#pragma unroll
  for (int r = 0; r < 16; ++r) im[r] = stc[swz(cnotL((lane << 4) | r))];

  // ===== combined RY round (folded, gt[60..69]), layout A =====
  cs = gt[66]; ry2<3>(re, im, cs.x, cs.y);
  cs = gt[67]; ry2<2>(re, im, cs.x, cs.y);
  cs = gt[68]; ry2<1>(re, im, cs.x, cs.y);
  cs = gt[69]; ry2<0>(re, im, cs.x, cs.y);
  cs = gt[64]; ry1_shfl<2>(lane, re, cs.x, cs.y); ry1_shfl<2>(lane, im, cs.x, cs.y);
  cs = gt[65]; ry1_shfl<1>(lane, re, cs.x, cs.y); ry1_shfl<1>(lane, im, cs.x, cs.y);

  // T3: A->B
#pragma unroll
  for (int r = 0; r < 16; ++r) stc[swz((lane << 4) | r)] = re[r];
#pragma unroll
  for (int r = 0; r < 16; ++r) re[r] = stc[swz((r << 6) | lane)];
#pragma unroll
  for (int r = 0; r < 16; ++r) stc[swz((lane << 4) | r)] = im[r];
#pragma unroll
  for (int r = 0; r < 16; ++r) im[r] = stc[swz((r << 6) | lane)];

  cs = gt[60]; ry2<3>(re, im, cs.x, cs.y);
  cs = gt[61]; ry2<2>(re, im, cs.x, cs.y);
  cs = gt[62]; ry2<1>(re, im, cs.x, cs.y);
  cs = gt[63]; ry2<0>(re, im, cs.x, cs.y);

  // RZ2 (table)
#pragma unroll
  for (int r = 0; r < 16; ++r) {
    const float2 t = rz2[(r << 6) | lane];
    const f2 nre = re[r] * t.x - im[r] * t.y;
    im[r] = re[r] * t.y + im[r] * t.x;
    re[r] = nre;
  }

  // T4: CNOT ring 2, gather read directly into layout B (final RY folded at output)
#pragma unroll
  for (int r = 0; r < 16; ++r) stc[swz((r << 6) | lane)] = re[r];
#pragma unroll
  for (int r = 0; r < 16; ++r) re[r] = stc[swz(cnotL((r << 6) | lane))];
#pragma unroll
  for (int r = 0; r < 16; ++r) stc[swz((r << 6) | lane)] = im[r];
#pragma unroll
  for (int r = 0; r < 16; ++r) im[r] = stc[swz(cnotL((r << 6) | lane))];

  // ===== expectation values (layout B), rows packed in f2 =====
  // acc order: [0..5]=X, [6..11]=Y, [12..17]=Z
  f2 a18[18];
#pragma unroll
  for (int k = 0; k < 12; ++k) a18[k] = (f2){0.f, 0.f};

  {
    f2 psum = (f2){0.f, 0.f};
    f2 z0 = (f2){0.f,0.f}, z1 = (f2){0.f,0.f}, z2 = (f2){0.f,0.f}, z3 = (f2){0.f,0.f};
#pragma unroll
    for (int r = 0; r < 16; ++r) {
      const f2 p = re[r] * re[r] + im[r] * im[r];
      psum += p;
      z0 += (r & 8) ? -p : p;
      z1 += (r & 4) ? -p : p;
      z2 += (r & 2) ? -p : p;
      z3 += (r & 1) ? -p : p;
    }
    a18[12] = z0; a18[13] = z1; a18[14] = z2; a18[15] = z3;
    a18[16] = ((lane >> 5) & 1) ? -psum : psum;   // Z q4
    a18[17] = ((lane >> 4) & 1) ? -psum : psum;   // Z q5
  }

  xyr<3>(re, im, a18[0], a18[6]);
  xyr<2>(re, im, a18[1], a18[7]);
  xyr<1>(re, im, a18[2], a18[8]);
  xyr<0>(re, im, a18[3], a18[9]);
  xys<32>(lane, re, im, a18[4], a18[10]);
  xys<16>(lane, re, im, a18[5], a18[11]);

  // --- distributed reduction: 2-step quad pre-reduce, then LDS combine ---
#pragma unroll
  for (int k = 0; k < 18; ++k) {
    f2 v = a18[k];
    v += dppf2<0xB1>(v);     // xor 1
    v += dppf2<0x4E>(v);     // xor 2  -> every lane in a quad holds the quad sum
    a18[k] = v;
  }
  float* red = reinterpret_cast<float*>(stc);     // reuse wave-private LDS (T4 done)
  if ((lane & 3) == 0) {
    const int q = lane >> 2;                      // quad id 0..15
    f2* redf2 = reinterpret_cast<f2*>(red);
#pragma unroll
    for (int k = 0; k < 18; ++k) redf2[q * 18 + k] = a18[k];
  }
  // Lanes 0..35: (c = row, j = observable). Sum 16 quad partials for own acc and
  // the Heisenberg partner (X<->Z), transform, store straight to out.
  if (lane < 36) {
    const int c  = (lane >= 18) ? 1 : 0;
    const int j  = lane - 18 * c;
    const int jq = (j < 6) ? j : ((j < 12) ? j - 6 : j - 12);
    const int jp = (j < 6) ? (j + 12) : ((j >= 12) ? (j - 12) : j);
    float S = 0.f, P = 0.f;
#pragma unroll
    for (int q = 0; q < 16; ++q) {
      S += red[(q * 18 + j ) * 2 + c];
      P += red[(q * 18 + jp) * 2 + c];
    }
    const float fac  = (jq < 4) ? 2.f : 1.f;      // xyr pairs once; xys twice
    const float2 fa  = gt[50 + jq];
    const float invc = c ? inv.y : inv.x;
    float o;
    if (j < 6)       o = (fac * S * fa.x + P * fa.y) * invc;        // X' = c*X + s*Z
    else if (j < 12) o = fac * S * invc;                            // Y' = Y
    else             o = (S * fa.x - fac * P * fa.y) * invc;        // Z' = c*Z - s*X
    if (c == 0 || has1) out[(size_t)(b0 + c) * 18 + j] = o;
  }
}

extern "C" void kernel_launch(void* const* d_in, const int* in_sizes, int n_in,
                              void* d_out, int out_size, void* d_ws, size_t ws_size,
                              hipStream_t stream) {
  const float* x = (const float*)d_in[0];
  const float* w = (const float*)d_in[1];
  float* out = (float*)d_out;
  float2* ws = (float2*)d_ws;
  const int B = in_sizes[0] / DIN;
  qae_prep<<<dim3(1), dim3(1024), 0, stream>>>(w, ws);
  const int grid = (B + 3) / 4;     // 2 waves/block x 2 rows/wave
  qae_main<<<dim3(grid), dim3(128), 0, stream>>>(x, (const float2*)ws, out, B);
}